// Round 2
// baseline (915.737 us; speedup 1.0000x reference)
//
#include <hip/hip_runtime.h>
#include <hip/hip_bf16.h>
#include <cstdint>

#define NEGV -1e30f

constexpr int B = 16, T = 1024, D = 512, V = 5000, L = 64;
constexpr int NJ = 66;   // col 0 (blank), col 1, 64 label columns
constexpr int NJP = 68;  // padded stride

__device__ __forceinline__ float lae2(float x, float y) {
    float m = fmaxf(x, y);
    float d = fminf(x, y) - m;          // <= 0 ; (-1e30)-(-1e30)=0 is safe
    return m + __logf(1.0f + __expf(d));
}
__device__ __forceinline__ float lae3(float x, float y, float z) {
    float m = fmaxf(fmaxf(x, y), z);
    float s = __expf(x - m) + __expf(y - m) + __expf(z - m);
    return m + __logf(s);
}

// ---------------- K1: gather W columns, bias, first-occurrence mask ----------
__global__ void k_gather(const float* __restrict__ W, const float* __restrict__ bias,
                         const int* __restrict__ ys,
                         float* __restrict__ Wgt, float* __restrict__ biasG,
                         unsigned* __restrict__ foMask) {
    int b = blockIdx.x, tid = threadIdx.x;
    __shared__ int cls[NJ];
    if (tid == 0) {
        cls[0] = 0; cls[1] = 1;
        for (int l = 0; l < L; ++l) cls[2 + l] = ys[b * L + l];
        unsigned m0 = 0, m1 = 0, m2 = 0;
        for (int j = 0; j < NJ; ++j) {
            bool first = true;
            for (int k = 0; k < j; ++k) if (cls[k] == cls[j]) { first = false; break; }
            if (first) {
                if (j < 32) m0 |= 1u << j;
                else if (j < 64) m1 |= 1u << (j - 32);
                else m2 |= 1u << (j - 64);
            }
        }
        foMask[b * 4 + 0] = m0; foMask[b * 4 + 1] = m1;
        foMask[b * 4 + 2] = m2; foMask[b * 4 + 3] = 0;
    }
    __syncthreads();
    if (tid < NJ) biasG[b * NJP + tid] = bias[cls[tid]];
    for (int i = tid; i < D * NJ; i += blockDim.x) {
        int d = i / NJ, j = i - d * NJ;
        Wgt[((size_t)b * D + d) * NJP + j] = W[(size_t)d * V + cls[j]];
    }
}

// ---------------- K2: masked scores + deduped LSE + log-probs ----------------
// grid (T/64, B), block 64 (1 wave). Lane = one time-row; 66 accumulators in
// VGPRs; W-gather rows are block-uniform -> scalar loads (SGPR operand FMAs).
__global__ __launch_bounds__(64) void k_scores(const float* __restrict__ hs,
        const float* __restrict__ Wgt, const float* __restrict__ biasG,
        const unsigned* __restrict__ foMask,
        float* __restrict__ lpb, float* __restrict__ lpl) {
    int b = blockIdx.y, t0 = blockIdx.x * 64, lane = threadIdx.x;
    const float* __restrict__ A  = hs  + ((size_t)b * T + t0) * D;
    const float* __restrict__ wg = Wgt + (size_t)b * D * NJP;
    __shared__ float As[64][133];          // pad 133: lane*5 mod 32 -> conflict-free reads
    float acc[NJ];
    #pragma unroll
    for (int j = 0; j < NJ; ++j) acc[j] = biasG[b * NJP + j];

    for (int kc = 0; kc < D; kc += 128) {
        __syncthreads();
        for (int i = lane; i < 64 * 32; i += 64) {   // stage 64 rows x 128 cols
            int r = i >> 5, c4 = i & 31;
            float4 v = *(const float4*)(A + (size_t)r * D + kc + c4 * 4);
            As[r][c4 * 4 + 0] = v.x; As[r][c4 * 4 + 1] = v.y;
            As[r][c4 * 4 + 2] = v.z; As[r][c4 * 4 + 3] = v.w;
        }
        __syncthreads();
        #pragma unroll 2
        for (int dd = 0; dd < 128; ++dd) {
            float a = As[lane][dd];
            const float* wrow = wg + (size_t)(kc + dd) * NJP;   // uniform
            #pragma unroll
            for (int j = 0; j < NJ; ++j) acc[j] = fmaf(a, wrow[j], acc[j]);
        }
    }

    unsigned m0 = foMask[b * 4 + 0], m1 = foMask[b * 4 + 1], m2 = foMask[b * 4 + 2];
    float mx = NEGV;
    #pragma unroll
    for (int j = 0; j < NJ; ++j) {
        bool on = (j < 32) ? ((m0 >> j) & 1) : (j < 64 ? ((m1 >> (j - 32)) & 1)
                                                       : ((m2 >> (j - 64)) & 1));
        if (on) mx = fmaxf(mx, acc[j]);
    }
    float ssum = 0.f;
    #pragma unroll
    for (int j = 0; j < NJ; ++j) {
        bool on = (j < 32) ? ((m0 >> j) & 1) : (j < 64 ? ((m1 >> (j - 32)) & 1)
                                                       : ((m2 >> (j - 64)) & 1));
        if (on) ssum += __expf(acc[j] - mx);
    }
    float lse = mx + __logf(ssum);

    int t = t0 + lane;
    lpb[b * T + t] = acc[0] - lse;
    float4* o = (float4*)(lpl + ((size_t)(b * T + t)) * 64);
    #pragma unroll
    for (int q = 0; q < 16; ++q)
        o[q] = make_float4(acc[2 + 4*q] - lse, acc[3 + 4*q] - lse,
                           acc[4 + 4*q] - lse, acc[5 + 4*q] - lse);
}

// ---------------- K3: CTC forward, one wave per batch, barrier-free ----------
// Lane l holds alpha[2l] (blank, aA) and alpha[2l+1] (label l, aB);
// lane 63 additionally holds alpha[128] (final blank, aE).
__global__ __launch_bounds__(64) void k_ctc(const float* __restrict__ lpb,
        const float* __restrict__ lpl, const int* __restrict__ ys,
        const int* __restrict__ hlens, const int* __restrict__ yslens,
        float* __restrict__ ll) {
    int b = blockIdx.x, l = threadIdx.x;
    int lab = ys[b * L + l];
    int labm1 = __shfl_up(lab, 1);
    bool skipB = (l >= 1) && (lab != 0) && (lab != labm1);  // skip for s=2l+1 (s>=3)
    int hlen = hlens[b];
    int s2 = 2 * yslens[b];
    const float* __restrict__ lpbb = lpb + b * T;
    const float* __restrict__ lplb = lpl + (size_t)b * T * 64;

    float lp0l = lplb[l];
    float aA = (l == 0) ? lpbb[0] : NEGV;   // alpha0[0] = lp(blank)
    float aB = (l == 0) ? lp0l    : NEGV;   // alpha0[1] = lp(label 0)
    float aE = NEGV;                        // alpha0[128]

    for (int t = 1; t < T; ++t) {
        float lpt_b = lpbb[t];                       // uniform scalar load
        float lpt_l = lplb[(size_t)t * 64 + l];      // coalesced
        float pA = __shfl_up(aA, 1);                 // alpha[2l-2]
        float pB = __shfl_up(aB, 1);                 // alpha[2l-1]
        if (l == 0) { pA = NEGV; pB = NEGV; }
        float nA = lae2(aA, pB) + lpt_b;                           // s = 2l
        float nB = lae3(aB, aA, skipB ? pA : NEGV) + lpt_l;        // s = 2l+1
        float nE = lae2(aE, aB) + lpt_b;                           // s = 128 (lane 63)
        if (t < hlen) { aA = nA; aB = nB; aE = nE; }
    }
    int s1 = s2 - 1;                                  // odd state 2*len-1
    float v1 = __shfl(aB, s1 >> 1);
    float v2 = (s2 >= 2 * L) ? __shfl(aE, 63) : __shfl(aA, s2 >> 1);
    if (l == 0) ll[b] = lae2(v1, v2);
}

// ---------------- K4: final reduction --------------------------------------
__global__ void k_final(const float* __restrict__ ll, float* __restrict__ out) {
    if (threadIdx.x == 0 && blockIdx.x == 0) {
        float s = 0.f;
        for (int i = 0; i < B; ++i) s += ll[i];
        out[0] = -s / (float)B;
    }
}

extern "C" void kernel_launch(void* const* d_in, const int* in_sizes, int n_in,
                              void* d_out, int out_size, void* d_ws, size_t ws_size,
                              hipStream_t stream) {
    const float* hs    = (const float*)d_in[0];
    const float* W     = (const float*)d_in[1];
    const float* bias  = (const float*)d_in[2];
    const int*  hlens  = (const int*)d_in[3];
    const int*  ys     = (const int*)d_in[4];
    const int*  yslens = (const int*)d_in[5];

    char* ws = (char*)d_ws;
    unsigned* foMask = (unsigned*)(ws);            // 256 B
    float* biasG = (float*)(ws + 256);             // 16*68*4 = 4352 -> ends 4608
    float* Wgt   = (float*)(ws + 4608);            // 16*512*68*4 = 2228224 -> 2232832
    float* lpb   = (float*)(ws + 2232832);         // 65536 -> 2298368
    float* lpl   = (float*)(ws + 2298368);         // 4194304 -> 6492672
    float* ll    = (float*)(ws + 6492672);         // 64

    hipLaunchKernelGGL(k_gather, dim3(B), dim3(256), 0, stream,
                       W, bias, ys, Wgt, biasG, foMask);
    hipLaunchKernelGGL(k_scores, dim3(T / 64, B), dim3(64), 0, stream,
                       hs, Wgt, biasG, foMask, lpb, lpl);
    hipLaunchKernelGGL(k_ctc, dim3(B), dim3(64), 0, stream,
                       lpb, lpl, ys, hlens, yslens, ll);
    hipLaunchKernelGGL(k_final, dim3(1), dim3(64), 0, stream, ll, (float*)d_out);
}

// Round 3
// 320.672 us; speedup vs baseline: 2.8557x; 2.8557x over previous
//
#include <hip/hip_runtime.h>
#include <hip/hip_bf16.h>
#include <cstdint>

#define NEGV -1e30f

constexpr int B = 16, T = 1024, D = 512, V = 5000, L = 64;
constexpr int NJ = 66;   // col 0 (blank), col 1, 64 label columns
constexpr int NJP = 68;  // padded stride (16B-aligned rows: 272B)
#define LOG2E 1.4426950408889634f
#define LN2   0.6931471805599453f

__device__ __forceinline__ float lae2_2(float x, float y) {  // log2 domain
    float m = fmaxf(x, y);
    float d = fminf(x, y) - m;
    return m + __log2f(1.0f + exp2f(d));
}
__device__ __forceinline__ float lae3_2(float x, float y, float z) {
    float m = fmaxf(fmaxf(x, y), z);
    float s = exp2f(x - m) + exp2f(y - m) + exp2f(z - m);
    return m + __log2f(s);
}

// ---------------- K1: gather W columns, bias, first-occurrence mask ----------
// grid (B, 8): block (b,c) gathers d in [64c, 64c+64). Mask/bias by c==0.
__global__ __launch_bounds__(256) void k_gather(const float* __restrict__ W,
        const float* __restrict__ bias, const int* __restrict__ ys,
        float* __restrict__ Wgt, float* __restrict__ biasG,
        unsigned* __restrict__ foMask) {
    int b = blockIdx.x, c = blockIdx.y, tid = threadIdx.x;
    __shared__ int cls[NJP];
    __shared__ unsigned mw[3];
    if (tid < NJP) cls[tid] = (tid < 2) ? tid : (tid < NJ ? ys[b * L + tid - 2] : 0);
    if (tid < 3) mw[tid] = 0u;
    __syncthreads();
    if (c == 0) {
        if (tid < NJ) {
            bool first = true;
            for (int k = 0; k < tid; ++k) if (cls[k] == cls[tid]) { first = false; break; }
            if (first) atomicOr(&mw[tid >> 5], 1u << (tid & 31));
        }
        __syncthreads();
        if (tid < 3) foMask[b * 4 + tid] = mw[tid];
        if (tid == 3) foMask[b * 4 + 3] = 0u;
        if (tid < NJP) biasG[b * NJP + tid] = (tid < NJ) ? bias[cls[tid]] : 0.f;
    }
    // gather: 64 d-rows x 68 cols (cols 66,67 zero-pad)
    for (int i = tid; i < 64 * NJP; i += 256) {
        int d = c * 64 + (i >> 6) * ((NJP == 68) ? 0 : 0) + i / NJP;  // i/NJP
        int j = i - (i / NJP) * NJP;
        d = c * 64 + i / NJP;
        float v = (j < NJ) ? W[(size_t)d * V + cls[j]] : 0.f;
        Wgt[((size_t)b * D + d) * NJP + j] = v;
    }
}

// ---------------- K2: fused masked GEMM + deduped LSE + log2-probs -----------
// grid (T/16, B), block 64 (1 wave). Wave tile: 16 rows x 68 cols.
// lane = (rg = lane&15 -> row, cg = lane>>4 -> cols [16cg,16cg+16)); cg0 also
// handles tail cols 64,65. A-chunk transposed + W-chunk staged in LDS.
__global__ __launch_bounds__(64) void k_scores(const float* __restrict__ hs,
        const float* __restrict__ Wgt, const float* __restrict__ biasG,
        const unsigned* __restrict__ foMask,
        float* __restrict__ lpb, float* __restrict__ lpl) {
    int b = blockIdx.y, t0 = blockIdx.x * 16;
    int lane = threadIdx.x, rg = lane & 15, cg = lane >> 4;
    __shared__ float Ast[64][17];   // [k][row], pad 17 to break write conflicts
    __shared__ float Ws[64][72];    // [k][col], stride 72 (288B, 16B-aligned)

    const float* __restrict__ bg = biasG + b * NJP;
    float acc[16], accE0, accE1;
    #pragma unroll
    for (int q = 0; q < 16; ++q) acc[q] = bg[16 * cg + q];
    accE0 = bg[64]; accE1 = bg[65];

    const float* __restrict__ hsb = hs + ((size_t)(b * T + t0)) * D;
    const float* __restrict__ wgb = Wgt + (size_t)b * D * NJP;

    int srow = lane & 15, kb = (lane >> 4) * 16;
    for (int kk = 0; kk < D; kk += 64) {
        // load to regs (global), then stage to LDS
        float4 a4[4];
        const float* src = hsb + (size_t)srow * D + kk + kb;
        #pragma unroll
        for (int q = 0; q < 4; ++q) a4[q] = *(const float4*)(src + q * 4);
        float4 w4[17];
        const float* wsrc = wgb + (size_t)(kk + lane) * NJP;
        #pragma unroll
        for (int q = 0; q < 17; ++q) w4[q] = *(const float4*)(wsrc + q * 4);
        __syncthreads();   // previous chunk fully consumed
        #pragma unroll
        for (int q = 0; q < 4; ++q) {
            Ast[kb + 4 * q + 0][srow] = a4[q].x;
            Ast[kb + 4 * q + 1][srow] = a4[q].y;
            Ast[kb + 4 * q + 2][srow] = a4[q].z;
            Ast[kb + 4 * q + 3][srow] = a4[q].w;
        }
        #pragma unroll
        for (int q = 0; q < 17; ++q) *(float4*)&Ws[lane][4 * q] = w4[q];
        __syncthreads();
        #pragma unroll 4
        for (int k = 0; k < 64; ++k) {
            float a = Ast[k][rg];
            float4 w0 = *(const float4*)&Ws[k][16 * cg + 0];
            float4 w1 = *(const float4*)&Ws[k][16 * cg + 4];
            float4 w2 = *(const float4*)&Ws[k][16 * cg + 8];
            float4 w3 = *(const float4*)&Ws[k][16 * cg + 12];
            acc[0]  = fmaf(a, w0.x, acc[0]);  acc[1]  = fmaf(a, w0.y, acc[1]);
            acc[2]  = fmaf(a, w0.z, acc[2]);  acc[3]  = fmaf(a, w0.w, acc[3]);
            acc[4]  = fmaf(a, w1.x, acc[4]);  acc[5]  = fmaf(a, w1.y, acc[5]);
            acc[6]  = fmaf(a, w1.z, acc[6]);  acc[7]  = fmaf(a, w1.w, acc[7]);
            acc[8]  = fmaf(a, w2.x, acc[8]);  acc[9]  = fmaf(a, w2.y, acc[9]);
            acc[10] = fmaf(a, w2.z, acc[10]); acc[11] = fmaf(a, w2.w, acc[11]);
            acc[12] = fmaf(a, w3.x, acc[12]); acc[13] = fmaf(a, w3.y, acc[13]);
            acc[14] = fmaf(a, w3.z, acc[14]); acc[15] = fmaf(a, w3.w, acc[15]);
            accE0   = fmaf(a, Ws[k][64], accE0);
            accE1   = fmaf(a, Ws[k][65], accE1);
        }
    }

    // deduped LSE over cols this lane owns, then 4-lane reduce (xor 16, 32)
    unsigned m0 = foMask[b * 4 + 0], m1 = foMask[b * 4 + 1], m2 = foMask[b * 4 + 2];
    unsigned mwrd = (cg < 2) ? m0 : m1;
    float mx = NEGV;
    #pragma unroll
    for (int q = 0; q < 16; ++q) {
        int sh = ((cg & 1) * 16) + q;
        if ((mwrd >> sh) & 1) mx = fmaxf(mx, acc[q]);
    }
    if (cg == 0) {
        if (m2 & 1u) mx = fmaxf(mx, accE0);
        if (m2 & 2u) mx = fmaxf(mx, accE1);
    }
    mx = fmaxf(mx, __shfl_xor(mx, 16));
    mx = fmaxf(mx, __shfl_xor(mx, 32));
    float s = 0.f;
    #pragma unroll
    for (int q = 0; q < 16; ++q) {
        int sh = ((cg & 1) * 16) + q;
        if ((mwrd >> sh) & 1) s += __expf(acc[q] - mx);
    }
    if (cg == 0) {
        if (m2 & 1u) s += __expf(accE0 - mx);
        if (m2 & 2u) s += __expf(accE1 - mx);
    }
    s += __shfl_xor(s, 16);
    s += __shfl_xor(s, 32);
    float lse = mx + __logf(s);

    // write log2-domain log-probs
    int row_g = b * T + t0 + rg;
    float* __restrict__ ol = lpl + (size_t)row_g * 64;
    if (cg == 0) {
        lpb[row_g] = (acc[0] - lse) * LOG2E;
        ol[62] = (accE0 - lse) * LOG2E;
        ol[63] = (accE1 - lse) * LOG2E;
        #pragma unroll
        for (int q = 2; q < 16; ++q) ol[q - 2] = (acc[q] - lse) * LOG2E;
    } else {
        #pragma unroll
        for (int q = 0; q < 16; ++q) ol[16 * cg + q - 2] = (acc[q] - lse) * LOG2E;
    }
}

// ---------------- K3: CTC forward (log2 domain), one wave per batch ----------
__global__ __launch_bounds__(64) void k_ctc(const float* __restrict__ lpb,
        const float* __restrict__ lpl, const int* __restrict__ ys,
        const int* __restrict__ hlens, const int* __restrict__ yslens,
        float* __restrict__ ll) {
    int b = blockIdx.x, l = threadIdx.x;
    int lab = ys[b * L + l];
    int labm1 = __shfl_up(lab, 1);
    bool skipB = (l >= 1) && (lab != 0) && (lab != labm1);
    int hlen = hlens[b];
    int s2 = 2 * yslens[b];
    const float* __restrict__ lpbb = lpb + b * T;
    const float* __restrict__ lplb = lpl + (size_t)b * T * 64;

    float aA = (l == 0) ? lpbb[0] : NEGV;
    float aB = (l == 0) ? lplb[0] : NEGV;
    float aE = NEGV;

    for (int t = 1; t < T; ++t) {
        float lpt_b = lpbb[t];
        float lpt_l = lplb[(size_t)t * 64 + l];
        float pA = __shfl_up(aA, 1);
        float pB = __shfl_up(aB, 1);
        if (l == 0) { pA = NEGV; pB = NEGV; }
        float nA = lae2_2(aA, pB) + lpt_b;
        float nB = lae3_2(aB, aA, skipB ? pA : NEGV) + lpt_l;
        float nE = lae2_2(aE, aB) + lpt_b;
        if (t < hlen) { aA = nA; aB = nB; aE = nE; }
    }
    int s1 = s2 - 1;
    float v1 = __shfl(aB, s1 >> 1);
    float v2 = (s2 >= 2 * L) ? __shfl(aE, 63) : __shfl(aA, s2 >> 1);
    if (l == 0) ll[b] = LN2 * lae2_2(v1, v2);
}

// ---------------- K4: final reduction --------------------------------------
__global__ void k_final(const float* __restrict__ ll, float* __restrict__ out) {
    if (threadIdx.x == 0 && blockIdx.x == 0) {
        float s = 0.f;
        for (int i = 0; i < B; ++i) s += ll[i];
        out[0] = -s / (float)B;
    }
}

extern "C" void kernel_launch(void* const* d_in, const int* in_sizes, int n_in,
                              void* d_out, int out_size, void* d_ws, size_t ws_size,
                              hipStream_t stream) {
    const float* hs    = (const float*)d_in[0];
    const float* W     = (const float*)d_in[1];
    const float* bias  = (const float*)d_in[2];
    const int*  hlens  = (const int*)d_in[3];
    const int*  ys     = (const int*)d_in[4];
    const int*  yslens = (const int*)d_in[5];

    char* ws = (char*)d_ws;
    unsigned* foMask = (unsigned*)(ws);            // 256 B
    float* biasG = (float*)(ws + 256);             // 16*68*4 -> ends 4608
    float* Wgt   = (float*)(ws + 4608);            // 16*512*68*4 -> 2232832
    float* lpb   = (float*)(ws + 2232832);         // 65536 -> 2298368
    float* lpl   = (float*)(ws + 2298368);         // 4194304 -> 6492672
    float* ll    = (float*)(ws + 6492672);         // 64

    hipLaunchKernelGGL(k_gather, dim3(B, 8), dim3(256), 0, stream,
                       W, bias, ys, Wgt, biasG, foMask);
    hipLaunchKernelGGL(k_scores, dim3(T / 16, B), dim3(64), 0, stream,
                       hs, Wgt, biasG, foMask, lpb, lpl);
    hipLaunchKernelGGL(k_ctc, dim3(B), dim3(64), 0, stream,
                       lpb, lpl, ys, hlens, yslens, ll);
    hipLaunchKernelGGL(k_final, dim3(1), dim3(64), 0, stream, ll, (float*)d_out);
}

// Round 4
// 235.956 us; speedup vs baseline: 3.8810x; 1.3590x over previous
//
#include <hip/hip_runtime.h>
#include <hip/hip_bf16.h>
#include <cstdint>

#define NEGV -1e30f

constexpr int B = 16, T = 1024, D = 512, V = 5000, L = 64;
constexpr int NJ = 66;   // col 0 (blank), col 1, 64 label columns
constexpr int NJP = 68;  // padded stride (16B-aligned rows: 272B)
#define LOG2E 1.4426950408889634f
#define LN2   0.6931471805599453f

__device__ __forceinline__ float lae2_2(float x, float y) {  // log2 domain
    float m = fmaxf(x, y);
    float d = fminf(x, y) - m;
    return m + __log2f(1.0f + exp2f(d));
}
__device__ __forceinline__ float lae3_2(float x, float y, float z) {
    float m = fmaxf(fmaxf(x, y), z);
    float s = exp2f(x - m) + exp2f(y - m) + exp2f(z - m);
    return m + __log2f(s);
}

// ---------------- K1: gather W columns, bias, first-occurrence mask ----------
// grid (B, 8): block (b,c) gathers d in [64c, 64c+64). Mask/bias by c==0.
__global__ __launch_bounds__(256) void k_gather(const float* __restrict__ W,
        const float* __restrict__ bias, const int* __restrict__ ys,
        float* __restrict__ Wgt, float* __restrict__ biasG,
        unsigned* __restrict__ foMask) {
    int b = blockIdx.x, c = blockIdx.y, tid = threadIdx.x;
    __shared__ int cls[NJP];
    __shared__ unsigned mw[3];
    if (tid < NJP) cls[tid] = (tid < 2) ? tid : (tid < NJ ? ys[b * L + tid - 2] : 0);
    if (tid < 3) mw[tid] = 0u;
    __syncthreads();
    if (c == 0) {
        if (tid < NJ) {
            bool first = true;
            for (int k = 0; k < tid; ++k) if (cls[k] == cls[tid]) { first = false; break; }
            if (first) atomicOr(&mw[tid >> 5], 1u << (tid & 31));
        }
        __syncthreads();
        if (tid < 3) foMask[b * 4 + tid] = mw[tid];
        if (tid == 3) foMask[b * 4 + 3] = 0u;
        if (tid < NJP) biasG[b * NJP + tid] = (tid < NJ) ? bias[cls[tid]] : 0.f;
    }
    // gather: 64 d-rows x 68 cols (cols 66,67 zero-pad)
    for (int i = tid; i < 64 * NJP; i += 256) {
        int d = c * 64 + i / NJP;
        int j = i - (i / NJP) * NJP;
        float v = (j < NJ) ? W[(size_t)d * V + cls[j]] : 0.f;
        Wgt[((size_t)b * D + d) * NJP + j] = v;
    }
}

// ---------------- K2: fused masked GEMM + deduped LSE + log2-probs -----------
// grid (T/16, B), block 64 (1 wave). Wave tile: 16 rows x 68 cols.
__global__ __launch_bounds__(64) void k_scores(const float* __restrict__ hs,
        const float* __restrict__ Wgt, const float* __restrict__ biasG,
        const unsigned* __restrict__ foMask,
        float* __restrict__ lpb, float* __restrict__ lpl) {
    int b = blockIdx.y, t0 = blockIdx.x * 16;
    int lane = threadIdx.x, rg = lane & 15, cg = lane >> 4;
    __shared__ float Ast[64][17];   // [k][row], pad 17 to break write conflicts
    __shared__ float Ws[64][72];    // [k][col], stride 72 (288B, 16B-aligned)

    const float* __restrict__ bg = biasG + b * NJP;
    float acc[16], accE0, accE1;
    #pragma unroll
    for (int q = 0; q < 16; ++q) acc[q] = bg[16 * cg + q];
    accE0 = bg[64]; accE1 = bg[65];

    const float* __restrict__ hsb = hs + ((size_t)(b * T + t0)) * D;
    const float* __restrict__ wgb = Wgt + (size_t)b * D * NJP;

    int srow = lane & 15, kb = (lane >> 4) * 16;
    for (int kk = 0; kk < D; kk += 64) {
        float4 a4[4];
        const float* src = hsb + (size_t)srow * D + kk + kb;
        #pragma unroll
        for (int q = 0; q < 4; ++q) a4[q] = *(const float4*)(src + q * 4);
        float4 w4[17];
        const float* wsrc = wgb + (size_t)(kk + lane) * NJP;
        #pragma unroll
        for (int q = 0; q < 17; ++q) w4[q] = *(const float4*)(wsrc + q * 4);
        __syncthreads();   // previous chunk fully consumed
        #pragma unroll
        for (int q = 0; q < 4; ++q) {
            Ast[kb + 4 * q + 0][srow] = a4[q].x;
            Ast[kb + 4 * q + 1][srow] = a4[q].y;
            Ast[kb + 4 * q + 2][srow] = a4[q].z;
            Ast[kb + 4 * q + 3][srow] = a4[q].w;
        }
        #pragma unroll
        for (int q = 0; q < 17; ++q) *(float4*)&Ws[lane][4 * q] = w4[q];
        __syncthreads();
        #pragma unroll 4
        for (int k = 0; k < 64; ++k) {
            float a = Ast[k][rg];
            float4 w0 = *(const float4*)&Ws[k][16 * cg + 0];
            float4 w1 = *(const float4*)&Ws[k][16 * cg + 4];
            float4 w2 = *(const float4*)&Ws[k][16 * cg + 8];
            float4 w3 = *(const float4*)&Ws[k][16 * cg + 12];
            acc[0]  = fmaf(a, w0.x, acc[0]);  acc[1]  = fmaf(a, w0.y, acc[1]);
            acc[2]  = fmaf(a, w0.z, acc[2]);  acc[3]  = fmaf(a, w0.w, acc[3]);
            acc[4]  = fmaf(a, w1.x, acc[4]);  acc[5]  = fmaf(a, w1.y, acc[5]);
            acc[6]  = fmaf(a, w1.z, acc[6]);  acc[7]  = fmaf(a, w1.w, acc[7]);
            acc[8]  = fmaf(a, w2.x, acc[8]);  acc[9]  = fmaf(a, w2.y, acc[9]);
            acc[10] = fmaf(a, w2.z, acc[10]); acc[11] = fmaf(a, w2.w, acc[11]);
            acc[12] = fmaf(a, w3.x, acc[12]); acc[13] = fmaf(a, w3.y, acc[13]);
            acc[14] = fmaf(a, w3.z, acc[14]); acc[15] = fmaf(a, w3.w, acc[15]);
            accE0   = fmaf(a, Ws[k][64], accE0);
            accE1   = fmaf(a, Ws[k][65], accE1);
        }
    }

    unsigned m0 = foMask[b * 4 + 0], m1 = foMask[b * 4 + 1], m2 = foMask[b * 4 + 2];
    unsigned mwrd = (cg < 2) ? m0 : m1;
    float mx = NEGV;
    #pragma unroll
    for (int q = 0; q < 16; ++q) {
        int sh = ((cg & 1) * 16) + q;
        if ((mwrd >> sh) & 1) mx = fmaxf(mx, acc[q]);
    }
    if (cg == 0) {
        if (m2 & 1u) mx = fmaxf(mx, accE0);
        if (m2 & 2u) mx = fmaxf(mx, accE1);
    }
    mx = fmaxf(mx, __shfl_xor(mx, 16));
    mx = fmaxf(mx, __shfl_xor(mx, 32));
    float s = 0.f;
    #pragma unroll
    for (int q = 0; q < 16; ++q) {
        int sh = ((cg & 1) * 16) + q;
        if ((mwrd >> sh) & 1) s += __expf(acc[q] - mx);
    }
    if (cg == 0) {
        if (m2 & 1u) s += __expf(accE0 - mx);
        if (m2 & 2u) s += __expf(accE1 - mx);
    }
    s += __shfl_xor(s, 16);
    s += __shfl_xor(s, 32);
    float lse = mx + __logf(s);

    int row_g = b * T + t0 + rg;
    float* __restrict__ ol = lpl + (size_t)row_g * 64;
    if (cg == 0) {
        lpb[row_g] = (acc[0] - lse) * LOG2E;
        ol[62] = (accE0 - lse) * LOG2E;
        ol[63] = (accE1 - lse) * LOG2E;
        #pragma unroll
        for (int q = 2; q < 16; ++q) ol[q - 2] = (acc[q] - lse) * LOG2E;
    } else {
        #pragma unroll
        for (int q = 0; q < 16; ++q) ol[16 * cg + q - 2] = (acc[q] - lse) * LOG2E;
    }
}

// ---------------- K3: CTC forward (log2 domain), one wave per batch ----------
// Serial in t; lp loads are NOT serial -> register prefetch pipeline (dist 16)
// + lpb staged in LDS. Lane l holds alpha[2l], alpha[2l+1]; lane 63 alpha[128].
__global__ __launch_bounds__(64) void k_ctc(const float* __restrict__ lpb,
        const float* __restrict__ lpl, const int* __restrict__ ys,
        const int* __restrict__ hlens, const int* __restrict__ yslens,
        float* __restrict__ ll) {
    int b = blockIdx.x, l = threadIdx.x;
    int lab = ys[b * L + l];
    int labm1 = __shfl_up(lab, 1);
    bool skipB = (l >= 1) && (lab != 0) && (lab != labm1);
    int hlen = hlens[b];
    int s2 = 2 * yslens[b];
    const float* __restrict__ lpbb = lpb + b * T;
    const float* __restrict__ lplb = lpl + (size_t)b * T * 64;

    __shared__ float Lb[T];
    #pragma unroll
    for (int i = 0; i < T / 64; ++i) Lb[i * 64 + l] = lpbb[i * 64 + l];
    __syncthreads();

    float aA = (l == 0) ? Lb[0]   : NEGV;   // alpha0[0]
    float aB = (l == 0) ? lplb[0] : NEGV;   // alpha0[1]
    float aE = NEGV;                        // alpha0[128] (lane 63)

    constexpr int PF = 16;
    float cur[PF], nxt[PF];
    #pragma unroll
    for (int u = 0; u < PF; ++u) {
        int tt = 1 + u; tt = tt < T ? tt : T - 1;
        cur[u] = lplb[(size_t)tt * 64 + l];
    }
    for (int t0 = 1; t0 < T; t0 += PF) {
        #pragma unroll
        for (int u = 0; u < PF; ++u) {           // prefetch group i+1
            int tt = t0 + PF + u; tt = tt < T ? tt : T - 1;
            nxt[u] = lplb[(size_t)tt * 64 + l];
        }
        #pragma unroll
        for (int u = 0; u < PF; ++u) {           // compute group i from regs
            int t = t0 + u;
            if (t < T) {
                float lpt_b = Lb[t];
                float lpt_l = cur[u];
                float pA = __shfl_up(aA, 1);     // alpha[2l-2]
                float pB = __shfl_up(aB, 1);     // alpha[2l-1]
                if (l == 0) pB = NEGV;           // pA masked via skipB==false at l=0
                float nA = lae2_2(aA, pB) + lpt_b;
                float nB = lae3_2(aB, aA, skipB ? pA : NEGV) + lpt_l;
                float nE = lae2_2(aE, aB) + lpt_b;
                if (t < hlen) { aA = nA; aB = nB; aE = nE; }
            }
        }
        #pragma unroll
        for (int u = 0; u < PF; ++u) cur[u] = nxt[u];
    }
    int s1 = s2 - 1;
    float v1 = __shfl(aB, s1 >> 1);
    float v2 = (s2 >= 2 * L) ? __shfl(aE, 63) : __shfl(aA, s2 >> 1);
    if (l == 0) ll[b] = LN2 * lae2_2(v1, v2);
}

// ---------------- K4: final reduction --------------------------------------
__global__ void k_final(const float* __restrict__ ll, float* __restrict__ out) {
    if (threadIdx.x == 0 && blockIdx.x == 0) {
        float s = 0.f;
        for (int i = 0; i < B; ++i) s += ll[i];
        out[0] = -s / (float)B;
    }
}

extern "C" void kernel_launch(void* const* d_in, const int* in_sizes, int n_in,
                              void* d_out, int out_size, void* d_ws, size_t ws_size,
                              hipStream_t stream) {
    const float* hs    = (const float*)d_in[0];
    const float* W     = (const float*)d_in[1];
    const float* bias  = (const float*)d_in[2];
    const int*  hlens  = (const int*)d_in[3];
    const int*  ys     = (const int*)d_in[4];
    const int*  yslens = (const int*)d_in[5];

    char* ws = (char*)d_ws;
    unsigned* foMask = (unsigned*)(ws);            // 256 B
    float* biasG = (float*)(ws + 256);             // -> 4608
    float* Wgt   = (float*)(ws + 4608);            // -> 2232832
    float* lpb   = (float*)(ws + 2232832);         // -> 2298368
    float* lpl   = (float*)(ws + 2298368);         // -> 6492672
    float* ll    = (float*)(ws + 6492672);         // 64

    hipLaunchKernelGGL(k_gather, dim3(B, 8), dim3(256), 0, stream,
                       W, bias, ys, Wgt, biasG, foMask);
    hipLaunchKernelGGL(k_scores, dim3(T / 16, B), dim3(64), 0, stream,
                       hs, Wgt, biasG, foMask, lpb, lpl);
    hipLaunchKernelGGL(k_ctc, dim3(B), dim3(64), 0, stream,
                       lpb, lpl, ys, hlens, yslens, ll);
    hipLaunchKernelGGL(k_final, dim3(1), dim3(64), 0, stream, ll, (float*)d_out);
}

// Round 5
// 221.920 us; speedup vs baseline: 4.1264x; 1.0632x over previous
//
#include <hip/hip_runtime.h>
#include <hip/hip_bf16.h>
#include <cstdint>

#define NEGV -1e30f

constexpr int B = 16, T = 1024, D = 512, V = 5000, L = 64;
constexpr int NJ = 66;   // col 0 (blank), col 1, 64 label columns
constexpr int NJP = 68;  // padded stride (16B-aligned rows: 272B)
#define LOG2E 1.4426950408889634f
#define LN2   0.6931471805599453f

__device__ __forceinline__ float lae2_2(float x, float y) {  // log2 domain
    float m = fmaxf(x, y);
    float d = fminf(x, y) - m;
    return m + __log2f(1.0f + exp2f(d));
}
__device__ __forceinline__ float lae3_2(float x, float y, float z) {
    float m = fmaxf(fmaxf(x, y), z);
    float s = exp2f(x - m) + exp2f(y - m) + exp2f(z - m);
    return m + __log2f(s);
}

// shfl_up by 1 across the full 64-lane wave via DPP wave_shr:1 (VALU, ~4 cy;
// no LDS pipe / lgkmcnt). Lane 0 (invalid source) receives `fill`.
__device__ __forceinline__ float shup1(float x, float fill) {
    int r = __builtin_amdgcn_update_dpp(__float_as_int(fill), __float_as_int(x),
                                        0x138 /*wave_shr:1*/, 0xf, 0xf, false);
    return __int_as_float(r);
}

// ---------------- K1: gather W columns, bias, first-occurrence mask ----------
// grid (B, 8): block (b,c) gathers d in [64c, 64c+64). Mask/bias by c==0.
__global__ __launch_bounds__(256) void k_gather(const float* __restrict__ W,
        const float* __restrict__ bias, const int* __restrict__ ys,
        float* __restrict__ Wgt, float* __restrict__ biasG,
        unsigned* __restrict__ foMask) {
    int b = blockIdx.x, c = blockIdx.y, tid = threadIdx.x;
    __shared__ int cls[NJP];
    __shared__ unsigned mw[3];
    if (tid < NJP) cls[tid] = (tid < 2) ? tid : (tid < NJ ? ys[b * L + tid - 2] : 0);
    if (tid < 3) mw[tid] = 0u;
    __syncthreads();
    if (c == 0) {
        if (tid < NJ) {
            bool first = true;
            for (int k = 0; k < tid; ++k) if (cls[k] == cls[tid]) { first = false; break; }
            if (first) atomicOr(&mw[tid >> 5], 1u << (tid & 31));
        }
        __syncthreads();
        if (tid < 3) foMask[b * 4 + tid] = mw[tid];
        if (tid == 3) foMask[b * 4 + 3] = 0u;
        if (tid < NJP) biasG[b * NJP + tid] = (tid < NJ) ? bias[cls[tid]] : 0.f;
    }
    // gather: 64 d-rows x 68 cols (cols 66,67 zero-pad)
    for (int i = tid; i < 64 * NJP; i += 256) {
        int d = c * 64 + i / NJP;
        int j = i - (i / NJP) * NJP;
        float v = (j < NJ) ? W[(size_t)d * V + cls[j]] : 0.f;
        Wgt[((size_t)b * D + d) * NJP + j] = v;
    }
}

// ---------------- K2: fused masked GEMM + deduped LSE + log2-probs -----------
// grid (T/16, B), block 64 (1 wave). Wave tile: 16 rows x 68 cols.
__global__ __launch_bounds__(64) void k_scores(const float* __restrict__ hs,
        const float* __restrict__ Wgt, const float* __restrict__ biasG,
        const unsigned* __restrict__ foMask,
        float* __restrict__ lpb, float* __restrict__ lpl) {
    int b = blockIdx.y, t0 = blockIdx.x * 16;
    int lane = threadIdx.x, rg = lane & 15, cg = lane >> 4;
    __shared__ float Ast[64][17];   // [k][row], pad 17 to break write conflicts
    __shared__ float Ws[64][72];    // [k][col], stride 72 (288B, 16B-aligned)

    const float* __restrict__ bg = biasG + b * NJP;
    float acc[16], accE0, accE1;
    #pragma unroll
    for (int q = 0; q < 16; ++q) acc[q] = bg[16 * cg + q];
    accE0 = bg[64]; accE1 = bg[65];

    const float* __restrict__ hsb = hs + ((size_t)(b * T + t0)) * D;
    const float* __restrict__ wgb = Wgt + (size_t)b * D * NJP;

    int srow = lane & 15, kb = (lane >> 4) * 16;
    for (int kk = 0; kk < D; kk += 64) {
        float4 a4[4];
        const float* src = hsb + (size_t)srow * D + kk + kb;
        #pragma unroll
        for (int q = 0; q < 4; ++q) a4[q] = *(const float4*)(src + q * 4);
        float4 w4[17];
        const float* wsrc = wgb + (size_t)(kk + lane) * NJP;
        #pragma unroll
        for (int q = 0; q < 17; ++q) w4[q] = *(const float4*)(wsrc + q * 4);
        __syncthreads();   // previous chunk fully consumed
        #pragma unroll
        for (int q = 0; q < 4; ++q) {
            Ast[kb + 4 * q + 0][srow] = a4[q].x;
            Ast[kb + 4 * q + 1][srow] = a4[q].y;
            Ast[kb + 4 * q + 2][srow] = a4[q].z;
            Ast[kb + 4 * q + 3][srow] = a4[q].w;
        }
        #pragma unroll
        for (int q = 0; q < 17; ++q) *(float4*)&Ws[lane][4 * q] = w4[q];
        __syncthreads();
        #pragma unroll 4
        for (int k = 0; k < 64; ++k) {
            float a = Ast[k][rg];
            float4 w0 = *(const float4*)&Ws[k][16 * cg + 0];
            float4 w1 = *(const float4*)&Ws[k][16 * cg + 4];
            float4 w2 = *(const float4*)&Ws[k][16 * cg + 8];
            float4 w3 = *(const float4*)&Ws[k][16 * cg + 12];
            acc[0]  = fmaf(a, w0.x, acc[0]);  acc[1]  = fmaf(a, w0.y, acc[1]);
            acc[2]  = fmaf(a, w0.z, acc[2]);  acc[3]  = fmaf(a, w0.w, acc[3]);
            acc[4]  = fmaf(a, w1.x, acc[4]);  acc[5]  = fmaf(a, w1.y, acc[5]);
            acc[6]  = fmaf(a, w1.z, acc[6]);  acc[7]  = fmaf(a, w1.w, acc[7]);
            acc[8]  = fmaf(a, w2.x, acc[8]);  acc[9]  = fmaf(a, w2.y, acc[9]);
            acc[10] = fmaf(a, w2.z, acc[10]); acc[11] = fmaf(a, w2.w, acc[11]);
            acc[12] = fmaf(a, w3.x, acc[12]); acc[13] = fmaf(a, w3.y, acc[13]);
            acc[14] = fmaf(a, w3.z, acc[14]); acc[15] = fmaf(a, w3.w, acc[15]);
            accE0   = fmaf(a, Ws[k][64], accE0);
            accE1   = fmaf(a, Ws[k][65], accE1);
        }
    }

    unsigned m0 = foMask[b * 4 + 0], m1 = foMask[b * 4 + 1], m2 = foMask[b * 4 + 2];
    unsigned mwrd = (cg < 2) ? m0 : m1;
    float mx = NEGV;
    #pragma unroll
    for (int q = 0; q < 16; ++q) {
        int sh = ((cg & 1) * 16) + q;
        if ((mwrd >> sh) & 1) mx = fmaxf(mx, acc[q]);
    }
    if (cg == 0) {
        if (m2 & 1u) mx = fmaxf(mx, accE0);
        if (m2 & 2u) mx = fmaxf(mx, accE1);
    }
    mx = fmaxf(mx, __shfl_xor(mx, 16));
    mx = fmaxf(mx, __shfl_xor(mx, 32));
    float s = 0.f;
    #pragma unroll
    for (int q = 0; q < 16; ++q) {
        int sh = ((cg & 1) * 16) + q;
        if ((mwrd >> sh) & 1) s += __expf(acc[q] - mx);
    }
    if (cg == 0) {
        if (m2 & 1u) s += __expf(accE0 - mx);
        if (m2 & 2u) s += __expf(accE1 - mx);
    }
    s += __shfl_xor(s, 16);
    s += __shfl_xor(s, 32);
    float lse = mx + __logf(s);

    int row_g = b * T + t0 + rg;
    float* __restrict__ ol = lpl + (size_t)row_g * 64;
    if (cg == 0) {
        lpb[row_g] = (acc[0] - lse) * LOG2E;
        ol[62] = (accE0 - lse) * LOG2E;
        ol[63] = (accE1 - lse) * LOG2E;
        #pragma unroll
        for (int q = 2; q < 16; ++q) ol[q - 2] = (acc[q] - lse) * LOG2E;
    } else {
        #pragma unroll
        for (int q = 0; q < 16; ++q) ol[16 * cg + q - 2] = (acc[q] - lse) * LOG2E;
    }
}

// ---------------- K3: CTC forward (log2 domain), one wave per batch ----------
// Serial in t. lp loads prefetched (dist 16); lpb staged in LDS; cross-lane
// alpha shift via DPP wave_shr:1 (VALU) instead of ds_bpermute (~120cy LDS).
__global__ __launch_bounds__(64) void k_ctc(const float* __restrict__ lpb,
        const float* __restrict__ lpl, const int* __restrict__ ys,
        const int* __restrict__ hlens, const int* __restrict__ yslens,
        float* __restrict__ ll) {
    int b = blockIdx.x, l = threadIdx.x;
    int lab = ys[b * L + l];
    int labm1 = __shfl_up(lab, 1);
    bool skipB = (l >= 1) && (lab != 0) && (lab != labm1);
    int hlen = hlens[b];
    int s2 = 2 * yslens[b];
    const float* __restrict__ lpbb = lpb + b * T;
    const float* __restrict__ lplb = lpl + (size_t)b * T * 64;

    __shared__ float Lb[T];
    #pragma unroll
    for (int i = 0; i < T / 64; ++i) Lb[i * 64 + l] = lpbb[i * 64 + l];
    __syncthreads();

    float aA = (l == 0) ? Lb[0]   : NEGV;   // alpha0[0]
    float aB = (l == 0) ? lplb[0] : NEGV;   // alpha0[1]
    float aE = NEGV;                        // alpha0[128] (lane 63)

    constexpr int PF = 16;
    float cur[PF], nxt[PF];
    #pragma unroll
    for (int u = 0; u < PF; ++u) {
        int tt = 1 + u; tt = tt < T ? tt : T - 1;
        cur[u] = lplb[(size_t)tt * 64 + l];
    }
    for (int t0 = 1; t0 < T; t0 += PF) {
        #pragma unroll
        for (int u = 0; u < PF; ++u) {           // prefetch group i+1
            int tt = t0 + PF + u; tt = tt < T ? tt : T - 1;
            nxt[u] = lplb[(size_t)tt * 64 + l];
        }
        #pragma unroll
        for (int u = 0; u < PF; ++u) {           // compute group i from regs
            int t = t0 + u;
            if (t < T) {
                float lpt_b = Lb[t];
                float lpt_l = cur[u];
                float pA = shup1(aA, NEGV);      // alpha[2l-2], lane0 -> NEGV
                float pB = shup1(aB, NEGV);      // alpha[2l-1], lane0 -> NEGV
                float nA = lae2_2(aA, pB) + lpt_b;
                float nB = lae3_2(aB, aA, skipB ? pA : NEGV) + lpt_l;
                float nE = lae2_2(aE, aB) + lpt_b;
                if (t < hlen) { aA = nA; aB = nB; aE = nE; }
            }
        }
        #pragma unroll
        for (int u = 0; u < PF; ++u) cur[u] = nxt[u];
    }
    int s1 = s2 - 1;
    float v1 = __shfl(aB, s1 >> 1);
    float v2 = (s2 >= 2 * L) ? __shfl(aE, 63) : __shfl(aA, s2 >> 1);
    if (l == 0) ll[b] = LN2 * lae2_2(v1, v2);
}

// ---------------- K4: final reduction --------------------------------------
__global__ void k_final(const float* __restrict__ ll, float* __restrict__ out) {
    if (threadIdx.x == 0 && blockIdx.x == 0) {
        float s = 0.f;
        for (int i = 0; i < B; ++i) s += ll[i];
        out[0] = -s / (float)B;
    }
}

extern "C" void kernel_launch(void* const* d_in, const int* in_sizes, int n_in,
                              void* d_out, int out_size, void* d_ws, size_t ws_size,
                              hipStream_t stream) {
    const float* hs    = (const float*)d_in[0];
    const float* W     = (const float*)d_in[1];
    const float* bias  = (const float*)d_in[2];
    const int*  hlens  = (const int*)d_in[3];
    const int*  ys     = (const int*)d_in[4];
    const int*  yslens = (const int*)d_in[5];

    char* ws = (char*)d_ws;
    unsigned* foMask = (unsigned*)(ws);            // 256 B
    float* biasG = (float*)(ws + 256);             // -> 4608
    float* Wgt   = (float*)(ws + 4608);            // -> 2232832
    float* lpb   = (float*)(ws + 2232832);         // -> 2298368
    float* lpl   = (float*)(ws + 2298368);         // -> 6492672
    float* ll    = (float*)(ws + 6492672);         // 64

    hipLaunchKernelGGL(k_gather, dim3(B, 8), dim3(256), 0, stream,
                       W, bias, ys, Wgt, biasG, foMask);
    hipLaunchKernelGGL(k_scores, dim3(T / 16, B), dim3(64), 0, stream,
                       hs, Wgt, biasG, foMask, lpb, lpl);
    hipLaunchKernelGGL(k_ctc, dim3(B), dim3(64), 0, stream,
                       lpb, lpl, ys, hlens, yslens, ll);
    hipLaunchKernelGGL(k_final, dim3(1), dim3(64), 0, stream, ll, (float*)d_out);
}

// Round 7
// 141.760 us; speedup vs baseline: 6.4598x; 1.5655x over previous
//
#include <hip/hip_runtime.h>
#include <hip/hip_bf16.h>
#include <cstdint>

#define NEGV -1e30f

constexpr int B = 16, T = 1024, D = 512, V = 5000, L = 64;
constexpr int NJ = 66;   // col 0 (blank), col 1, 64 label columns
constexpr int NJP = 68;  // padded stride (16B-aligned rows: 272B)
#define LOG2E 1.4426950408889634f
#define LN2   0.6931471805599453f
#define PSH   6.0f   // probs pre-scaled by 2^6 so per-step decay ~1

template <int CTRL>
__device__ __forceinline__ float dppf(float x) {
    return __int_as_float(__builtin_amdgcn_update_dpp(
        __float_as_int(x), __float_as_int(x), CTRL, 0xf, 0xf, false));
}
// shfl_up 1 across 64 lanes, lane0 <- fill (VALU DPP, no LDS pipe)
__device__ __forceinline__ float shup1(float x, float fill) {
    int r = __builtin_amdgcn_update_dpp(__float_as_int(fill), __float_as_int(x),
                                        0x138 /*wave_shr:1*/, 0xf, 0xf, false);
    return __int_as_float(r);
}
// wave64 max -> uniform value in all lanes (DPP tree + readlane)
__device__ __forceinline__ float wmax64(float x) {
    x = fmaxf(x, dppf<0x111>(x));  // row_shr:1
    x = fmaxf(x, dppf<0x112>(x));  // row_shr:2
    x = fmaxf(x, dppf<0x114>(x));  // row_shr:4
    x = fmaxf(x, dppf<0x118>(x));  // row_shr:8
    x = fmaxf(x, dppf<0x142>(x));  // row_bcast:15
    x = fmaxf(x, dppf<0x143>(x));  // row_bcast:31
    return __int_as_float(__builtin_amdgcn_readlane(__float_as_int(x), 63));
}

// ---------------- K1: gather W columns, bias, first-occurrence mask ----------
__global__ __launch_bounds__(256) void k_gather(const float* __restrict__ W,
        const float* __restrict__ bias, const int* __restrict__ ys,
        float* __restrict__ Wgt, float* __restrict__ biasG,
        unsigned* __restrict__ foMask) {
    int b = blockIdx.x, c = blockIdx.y, tid = threadIdx.x;
    __shared__ int cls[NJP];
    __shared__ unsigned mw[3];
    if (tid < NJP) cls[tid] = (tid < 2) ? tid : (tid < NJ ? ys[b * L + tid - 2] : 0);
    if (tid < 3) mw[tid] = 0u;
    __syncthreads();
    if (c == 0) {
        if (tid < NJ) {
            bool first = true;
            for (int k = 0; k < tid; ++k) if (cls[k] == cls[tid]) { first = false; break; }
            if (first) atomicOr(&mw[tid >> 5], 1u << (tid & 31));
        }
        __syncthreads();
        if (tid < 3) foMask[b * 4 + tid] = mw[tid];
        if (tid == 3) foMask[b * 4 + 3] = 0u;
        if (tid < NJP) biasG[b * NJP + tid] = (tid < NJ) ? bias[cls[tid]] : 0.f;
    }
    for (int i = tid; i < 64 * NJP; i += 256) {
        int d = c * 64 + i / NJP;
        int j = i - (i / NJP) * NJP;
        float v = (j < NJ) ? W[(size_t)d * V + cls[j]] : 0.f;
        Wgt[((size_t)b * D + d) * NJP + j] = v;
    }
}

// ---------------- K2: fused masked GEMM + deduped LSE -> scaled linear probs -
// grid (T/16, B), block 64 (1 wave). Wave tile: 16 rows x 68 cols.
// Outputs p = exp2(log2-prob + 6) (linear domain, 2^6-scaled) coalesced via
// an LDS transpose of the 16x64 tile.
__global__ __launch_bounds__(64) void k_scores(const float* __restrict__ hs,
        const float* __restrict__ Wgt, const float* __restrict__ biasG,
        const unsigned* __restrict__ foMask,
        float* __restrict__ lpb, float* __restrict__ lpl) {
    int b = blockIdx.y, t0 = blockIdx.x * 16;
    int lane = threadIdx.x, rg = lane & 15, cg = lane >> 4;
    __shared__ float Ast[64][17];   // [k][row]
    __shared__ float Ws[64][72];    // [k][col]

    const float* __restrict__ bg = biasG + b * NJP;
    float acc[16], accE0, accE1;
    #pragma unroll
    for (int q = 0; q < 16; ++q) acc[q] = bg[16 * cg + q];
    accE0 = bg[64]; accE1 = bg[65];

    const float* __restrict__ hsb = hs + ((size_t)(b * T + t0)) * D;
    const float* __restrict__ wgb = Wgt + (size_t)b * D * NJP;

    int srow = lane & 15, kb = (lane >> 4) * 16;
    for (int kk = 0; kk < D; kk += 64) {
        float4 a4[4];
        const float* src = hsb + (size_t)srow * D + kk + kb;
        #pragma unroll
        for (int q = 0; q < 4; ++q) a4[q] = *(const float4*)(src + q * 4);
        float4 w4[17];
        const float* wsrc = wgb + (size_t)(kk + lane) * NJP;
        #pragma unroll
        for (int q = 0; q < 17; ++q) w4[q] = *(const float4*)(wsrc + q * 4);
        __syncthreads();
        #pragma unroll
        for (int q = 0; q < 4; ++q) {
            Ast[kb + 4 * q + 0][srow] = a4[q].x;
            Ast[kb + 4 * q + 1][srow] = a4[q].y;
            Ast[kb + 4 * q + 2][srow] = a4[q].z;
            Ast[kb + 4 * q + 3][srow] = a4[q].w;
        }
        #pragma unroll
        for (int q = 0; q < 17; ++q) *(float4*)&Ws[lane][4 * q] = w4[q];
        __syncthreads();
        #pragma unroll 4
        for (int k = 0; k < 64; ++k) {
            float a = Ast[k][rg];
            float4 w0 = *(const float4*)&Ws[k][16 * cg + 0];
            float4 w1 = *(const float4*)&Ws[k][16 * cg + 4];
            float4 w2 = *(const float4*)&Ws[k][16 * cg + 8];
            float4 w3 = *(const float4*)&Ws[k][16 * cg + 12];
            acc[0]  = fmaf(a, w0.x, acc[0]);  acc[1]  = fmaf(a, w0.y, acc[1]);
            acc[2]  = fmaf(a, w0.z, acc[2]);  acc[3]  = fmaf(a, w0.w, acc[3]);
            acc[4]  = fmaf(a, w1.x, acc[4]);  acc[5]  = fmaf(a, w1.y, acc[5]);
            acc[6]  = fmaf(a, w1.z, acc[6]);  acc[7]  = fmaf(a, w1.w, acc[7]);
            acc[8]  = fmaf(a, w2.x, acc[8]);  acc[9]  = fmaf(a, w2.y, acc[9]);
            acc[10] = fmaf(a, w2.z, acc[10]); acc[11] = fmaf(a, w2.w, acc[11]);
            acc[12] = fmaf(a, w3.x, acc[12]); acc[13] = fmaf(a, w3.y, acc[13]);
            acc[14] = fmaf(a, w3.z, acc[14]); acc[15] = fmaf(a, w3.w, acc[15]);
            accE0   = fmaf(a, Ws[k][64], accE0);
            accE1   = fmaf(a, Ws[k][65], accE1);
        }
    }

    unsigned m0 = foMask[b * 4 + 0], m1 = foMask[b * 4 + 1], m2 = foMask[b * 4 + 2];
    unsigned mwrd = (cg < 2) ? m0 : m1;
    float mx = NEGV;
    #pragma unroll
    for (int q = 0; q < 16; ++q) {
        int sh = ((cg & 1) * 16) + q;
        if ((mwrd >> sh) & 1) mx = fmaxf(mx, acc[q]);
    }
    if (cg == 0) {
        if (m2 & 1u) mx = fmaxf(mx, accE0);
        if (m2 & 2u) mx = fmaxf(mx, accE1);
    }
    mx = fmaxf(mx, __shfl_xor(mx, 16));
    mx = fmaxf(mx, __shfl_xor(mx, 32));
    float s = 0.f;
    #pragma unroll
    for (int q = 0; q < 16; ++q) {
        int sh = ((cg & 1) * 16) + q;
        if ((mwrd >> sh) & 1) s += __expf(acc[q] - mx);
    }
    if (cg == 0) {
        if (m2 & 1u) s += __expf(accE0 - mx);
        if (m2 & 2u) s += __expf(accE1 - mx);
    }
    s += __shfl_xor(s, 16);
    s += __shfl_xor(s, 32);
    float lse = mx + __logf(s);

    // epilogue: p = exp2(lp2 + 6), transposed through LDS, coalesced stores
    float (*Pt)[72] = (float(*)[72])&Ws[0][0];   // 16 x 72 reuse
    __syncthreads();
    int row_g = b * T + t0 + rg;
    if (cg == 0) {
        lpb[row_g] = exp2f((acc[0] - lse) * LOG2E + PSH);
        Pt[rg][62] = exp2f((accE0 - lse) * LOG2E + PSH);
        Pt[rg][63] = exp2f((accE1 - lse) * LOG2E + PSH);
        #pragma unroll
        for (int q = 2; q < 16; ++q)
            Pt[rg][q - 2] = exp2f((acc[q] - lse) * LOG2E + PSH);
    } else {
        #pragma unroll
        for (int q = 0; q < 16; ++q)
            Pt[rg][16 * cg + q - 2] = exp2f((acc[q] - lse) * LOG2E + PSH);
    }
    __syncthreads();
    int base = b * T + t0;
    #pragma unroll
    for (int r = 0; r < 16; ++r)
        lpl[(size_t)(base + r) * 64 + lane] = Pt[r][lane];
}

// ---------------- K3: CTC forward, LINEAR domain, one wave per batch ---------
// nB = (aB + aA + sel(pA)) * p : add->add->mul chain (~12-16 cy), no
// transcendentals. Probs pre-scaled 2^6; wave-uniform renorm every 8 steps
// (DPP wave-max, exact pow2 rescale, Esum tracks exponents).
__global__ __launch_bounds__(64) void k_ctc(const float* __restrict__ lpb,
        const float* __restrict__ lpl, const int* __restrict__ ys,
        const int* __restrict__ hlens, const int* __restrict__ yslens,
        float* __restrict__ ll) {
    int b = blockIdx.x, l = threadIdx.x;
    int lab = ys[b * L + l];
    int labm1 = __shfl_up(lab, 1);
    bool skipB = (l >= 1) && (lab != 0) && (lab != labm1);
    int hlen = hlens[b];
    int s2 = 2 * yslens[b];
    const float* __restrict__ lpbb = lpb + b * T;
    const float* __restrict__ lplb = lpl + (size_t)b * T * 64;

    __shared__ float Lb[T];
    #pragma unroll
    for (int i = 0; i < T / 64; ++i) Lb[i * 64 + l] = lpbb[i * 64 + l];
    __syncthreads();

    float aA = (l == 0) ? Lb[0]   : 0.f;   // alpha0[0]
    float aB = (l == 0) ? lplb[0] : 0.f;   // alpha0[1]
    float aE = 0.f;                        // alpha0[128] (lane 63)
    int Esum = 0;

    constexpr int PF = 16;
    float cur[PF], nxt[PF];
    #pragma unroll
    for (int u = 0; u < PF; ++u) {
        int tt = 1 + u; tt = tt < T ? tt : T - 1;
        cur[u] = lplb[(size_t)tt * 64 + l];
    }
    for (int t0 = 1; t0 < T; t0 += PF) {
        #pragma unroll
        for (int u = 0; u < PF; ++u) {           // prefetch group i+1
            int tt = t0 + PF + u; tt = tt < T ? tt : T - 1;
            nxt[u] = lplb[(size_t)tt * 64 + l];
        }
        #pragma unroll
        for (int u = 0; u < PF; ++u) {           // compute group i from regs
            int t = t0 + u;
            if (t < T) {
                float p_b = Lb[t];
                float p_l = cur[u];
                float pA = shup1(aA, 0.f);       // alpha[2l-2]
                float pB = shup1(aB, 0.f);       // alpha[2l-1]
                float sp = skipB ? pA : 0.f;
                float nA = (aA + pB) * p_b;
                float nB = (aB + aA + sp) * p_l;
                float nE = (aE + aB) * p_b;
                if (t < hlen) { aA = nA; aB = nB; aE = nE; }
            }
            if ((u & 7) == 7) {                  // renorm every 8 steps
                float m = wmax64(fmaxf(fmaxf(aA, aB), aE));
                int e = ((__float_as_int(m) >> 23) & 255) - 127;
                float sc = __int_as_float((127 - e) << 23);  // exact 2^-e
                aA *= sc; aB *= sc; aE *= sc; Esum += e;
            }
        }
        #pragma unroll
        for (int u = 0; u < PF; ++u) cur[u] = nxt[u];
    }
    int s1 = s2 - 1;
    float v1 = __shfl(aB, s1 >> 1);
    float v2 = (s2 >= 2 * L) ? __shfl(aE, 63) : __shfl(aA, s2 >> 1);
    if (l == 0)
        ll[b] = LN2 * (__log2f(v1 + v2) + (float)Esum - PSH * (float)hlen);
}

// ---------------- K4: final reduction --------------------------------------
__global__ void k_final(const float* __restrict__ ll, float* __restrict__ out) {
    if (threadIdx.x == 0 && blockIdx.x == 0) {
        float s = 0.f;
        for (int i = 0; i < B; ++i) s += ll[i];
        out[0] = -s / (float)B;
    }
}

extern "C" void kernel_launch(void* const* d_in, const int* in_sizes, int n_in,
                              void* d_out, int out_size, void* d_ws, size_t ws_size,
                              hipStream_t stream) {
    const float* hs    = (const float*)d_in[0];
    const float* W     = (const float*)d_in[1];
    const float* bias  = (const float*)d_in[2];
    const int*  hlens  = (const int*)d_in[3];
    const int*  ys     = (const int*)d_in[4];
    const int*  yslens = (const int*)d_in[5];

    char* ws = (char*)d_ws;
    unsigned* foMask = (unsigned*)(ws);            // 256 B
    float* biasG = (float*)(ws + 256);             // -> 4608
    float* Wgt   = (float*)(ws + 4608);            // -> 2232832
    float* lpb   = (float*)(ws + 2232832);         // -> 2298368
    float* lpl   = (float*)(ws + 2298368);         // -> 6492672
    float* ll    = (float*)(ws + 6492672);         // 64

    hipLaunchKernelGGL(k_gather, dim3(B, 8), dim3(256), 0, stream,
                       W, bias, ys, Wgt, biasG, foMask);
    hipLaunchKernelGGL(k_scores, dim3(T / 16, B), dim3(64), 0, stream,
                       hs, Wgt, biasG, foMask, lpb, lpl);
    hipLaunchKernelGGL(k_ctc, dim3(B), dim3(64), 0, stream,
                       lpb, lpl, ys, hlens, yslens, ll);
    hipLaunchKernelGGL(k_final, dim3(1), dim3(64), 0, stream, ll, (float*)d_out);
}

// Round 8
// 132.792 us; speedup vs baseline: 6.8960x; 1.0675x over previous
//
#include <hip/hip_runtime.h>
#include <hip/hip_bf16.h>
#include <cstdint>

#define NEGV -1e30f

constexpr int B = 16, T = 1024, D = 512, V = 5000, L = 64;
constexpr int NJ = 66;   // col 0 (blank), col 1, 64 label columns
constexpr int NJP = 68;  // padded stride (16B-aligned rows: 272B)
#define LOG2E 1.4426950408889634f
#define LN2   0.6931471805599453f
#define PSH   6.0f   // probs pre-scaled by 2^6 so per-step decay ~1

template <int CTRL>
__device__ __forceinline__ float dppf(float x) {
    return __int_as_float(__builtin_amdgcn_update_dpp(
        __float_as_int(x), __float_as_int(x), CTRL, 0xf, 0xf, false));
}
// shfl_up 1 across 64 lanes, lane0 <- fill (VALU DPP, no LDS pipe)
__device__ __forceinline__ float shup1(float x, float fill) {
    int r = __builtin_amdgcn_update_dpp(__float_as_int(fill), __float_as_int(x),
                                        0x138 /*wave_shr:1*/, 0xf, 0xf, false);
    return __int_as_float(r);
}
// wave64 max -> uniform value in all lanes (DPP tree + readlane)
__device__ __forceinline__ float wmax64(float x) {
    x = fmaxf(x, dppf<0x111>(x));  // row_shr:1
    x = fmaxf(x, dppf<0x112>(x));  // row_shr:2
    x = fmaxf(x, dppf<0x114>(x));  // row_shr:4
    x = fmaxf(x, dppf<0x118>(x));  // row_shr:8
    x = fmaxf(x, dppf<0x142>(x));  // row_bcast:15
    x = fmaxf(x, dppf<0x143>(x));  // row_bcast:31
    return __int_as_float(__builtin_amdgcn_readlane(__float_as_int(x), 63));
}

// one linear-domain CTC step (add->add->mul chain, no transcendentals)
__device__ __forceinline__ void ctc_step(float& aA, float& aB, float& aE,
        float p_b, float p_l, bool skipB, bool upd) {
    float pA = shup1(aA, 0.f);           // alpha[2l-2]
    float pB = shup1(aB, 0.f);           // alpha[2l-1]
    float sp = skipB ? pA : 0.f;
    float nA = (aA + pB) * p_b;
    float nB = (aB + aA + sp) * p_l;
    float nE = (aE + aB) * p_b;
    if (upd) { aA = nA; aB = nB; aE = nE; }
}
__device__ __forceinline__ void renorm(float& aA, float& aB, float& aE, int& Esum) {
    float m = wmax64(fmaxf(fmaxf(aA, aB), aE));
    int e = ((__float_as_int(m) >> 23) & 255) - 127;
    float sc = __int_as_float((127 - e) << 23);   // exact 2^-e
    aA *= sc; aB *= sc; aE *= sc; Esum += e;
}

// ---------------- K1: gather W columns, bias, first-occurrence mask ----------
__global__ __launch_bounds__(256) void k_gather(const float* __restrict__ W,
        const float* __restrict__ bias, const int* __restrict__ ys,
        float* __restrict__ Wgt, float* __restrict__ biasG,
        unsigned* __restrict__ foMask) {
    int b = blockIdx.x, c = blockIdx.y, tid = threadIdx.x;
    __shared__ int cls[NJP];
    __shared__ unsigned mw[3];
    if (tid < NJP) cls[tid] = (tid < 2) ? tid : (tid < NJ ? ys[b * L + tid - 2] : 0);
    if (tid < 3) mw[tid] = 0u;
    __syncthreads();
    if (c == 0) {
        if (tid < NJ) {
            bool first = true;
            for (int k = 0; k < tid; ++k) if (cls[k] == cls[tid]) { first = false; break; }
            if (first) atomicOr(&mw[tid >> 5], 1u << (tid & 31));
        }
        __syncthreads();
        if (tid < 3) foMask[b * 4 + tid] = mw[tid];
        if (tid == 3) foMask[b * 4 + 3] = 0u;
        if (tid < NJP) biasG[b * NJP + tid] = (tid < NJ) ? bias[cls[tid]] : 0.f;
    }
    for (int i = tid; i < 64 * NJP; i += 256) {
        int d = c * 64 + i / NJP;
        int j = i - (i / NJP) * NJP;
        float v = (j < NJ) ? W[(size_t)d * V + cls[j]] : 0.f;
        Wgt[((size_t)b * D + d) * NJP + j] = v;
    }
}

// ---------------- K2: fused masked GEMM + deduped LSE -> scaled linear probs -
// grid (T/16, B), block 64 (1 wave). Wave tile: 16 rows(t) x 68 cols.
// Output lplT layout [b][label l][t] so k_ctc lanes stream contiguously.
// ALL global stores are float4 (sub-16B stores cost a full 128B HBM line).
__global__ __launch_bounds__(64) void k_scores(const float* __restrict__ hs,
        const float* __restrict__ Wgt, const float* __restrict__ biasG,
        const unsigned* __restrict__ foMask,
        float* __restrict__ lpb, float* __restrict__ lplT) {
    int b = blockIdx.y, t0 = blockIdx.x * 16;
    int lane = threadIdx.x, rg = lane & 15, cg = lane >> 4;
    __shared__ float Ast[64][17];   // [k][row]
    __shared__ float Ws[64][72];    // [k][col]

    const float* __restrict__ bg = biasG + b * NJP;
    float acc[16], accE0, accE1;
    #pragma unroll
    for (int q = 0; q < 16; ++q) acc[q] = bg[16 * cg + q];
    accE0 = bg[64]; accE1 = bg[65];

    const float* __restrict__ hsb = hs + ((size_t)(b * T + t0)) * D;
    const float* __restrict__ wgb = Wgt + (size_t)b * D * NJP;

    int srow = lane & 15, kb = (lane >> 4) * 16;
    for (int kk = 0; kk < D; kk += 64) {
        float4 a4[4];
        const float* src = hsb + (size_t)srow * D + kk + kb;
        #pragma unroll
        for (int q = 0; q < 4; ++q) a4[q] = *(const float4*)(src + q * 4);
        float4 w4[17];
        const float* wsrc = wgb + (size_t)(kk + lane) * NJP;
        #pragma unroll
        for (int q = 0; q < 17; ++q) w4[q] = *(const float4*)(wsrc + q * 4);
        __syncthreads();
        #pragma unroll
        for (int q = 0; q < 4; ++q) {
            Ast[kb + 4 * q + 0][srow] = a4[q].x;
            Ast[kb + 4 * q + 1][srow] = a4[q].y;
            Ast[kb + 4 * q + 2][srow] = a4[q].z;
            Ast[kb + 4 * q + 3][srow] = a4[q].w;
        }
        #pragma unroll
        for (int q = 0; q < 17; ++q) *(float4*)&Ws[lane][4 * q] = w4[q];
        __syncthreads();
        #pragma unroll 4
        for (int k = 0; k < 64; ++k) {
            float a = Ast[k][rg];
            float4 w0 = *(const float4*)&Ws[k][16 * cg + 0];
            float4 w1 = *(const float4*)&Ws[k][16 * cg + 4];
            float4 w2 = *(const float4*)&Ws[k][16 * cg + 8];
            float4 w3 = *(const float4*)&Ws[k][16 * cg + 12];
            acc[0]  = fmaf(a, w0.x, acc[0]);  acc[1]  = fmaf(a, w0.y, acc[1]);
            acc[2]  = fmaf(a, w0.z, acc[2]);  acc[3]  = fmaf(a, w0.w, acc[3]);
            acc[4]  = fmaf(a, w1.x, acc[4]);  acc[5]  = fmaf(a, w1.y, acc[5]);
            acc[6]  = fmaf(a, w1.z, acc[6]);  acc[7]  = fmaf(a, w1.w, acc[7]);
            acc[8]  = fmaf(a, w2.x, acc[8]);  acc[9]  = fmaf(a, w2.y, acc[9]);
            acc[10] = fmaf(a, w2.z, acc[10]); acc[11] = fmaf(a, w2.w, acc[11]);
            acc[12] = fmaf(a, w3.x, acc[12]); acc[13] = fmaf(a, w3.y, acc[13]);
            acc[14] = fmaf(a, w3.z, acc[14]); acc[15] = fmaf(a, w3.w, acc[15]);
            accE0   = fmaf(a, Ws[k][64], accE0);
            accE1   = fmaf(a, Ws[k][65], accE1);
        }
    }

    unsigned m0 = foMask[b * 4 + 0], m1 = foMask[b * 4 + 1], m2 = foMask[b * 4 + 2];
    unsigned mwrd = (cg < 2) ? m0 : m1;
    float mx = NEGV;
    #pragma unroll
    for (int q = 0; q < 16; ++q) {
        int sh = ((cg & 1) * 16) + q;
        if ((mwrd >> sh) & 1) mx = fmaxf(mx, acc[q]);
    }
    if (cg == 0) {
        if (m2 & 1u) mx = fmaxf(mx, accE0);
        if (m2 & 2u) mx = fmaxf(mx, accE1);
    }
    mx = fmaxf(mx, __shfl_xor(mx, 16));
    mx = fmaxf(mx, __shfl_xor(mx, 32));
    float s = 0.f;
    #pragma unroll
    for (int q = 0; q < 16; ++q) {
        int sh = ((cg & 1) * 16) + q;
        if ((mwrd >> sh) & 1) s += __expf(acc[q] - mx);
    }
    if (cg == 0) {
        if (m2 & 1u) s += __expf(accE0 - mx);
        if (m2 & 2u) s += __expf(accE1 - mx);
    }
    s += __shfl_xor(s, 16);
    s += __shfl_xor(s, 32);
    float lse = mx + __logf(s);

    // epilogue: p = exp2(lp2+6); transpose to [label][t_local] in LDS, then
    // each lane stores its label-row as 4x float4 (16B stores merge at HBM).
    float (*Pt2)[17] = (float(*)[17])&Ws[0][0];   // 64 labels x 16 t (pad 17)
    float* Pb = &Ast[0][0];                        // 16 blanks
    __syncthreads();
    if (cg == 0) {
        Pb[rg]      = exp2f((acc[0] - lse) * LOG2E + PSH);
        Pt2[62][rg] = exp2f((accE0 - lse) * LOG2E + PSH);
        Pt2[63][rg] = exp2f((accE1 - lse) * LOG2E + PSH);
        #pragma unroll
        for (int q = 2; q < 16; ++q)
            Pt2[q - 2][rg] = exp2f((acc[q] - lse) * LOG2E + PSH);
    } else {
        #pragma unroll
        for (int q = 0; q < 16; ++q)
            Pt2[16 * cg + q - 2][rg] = exp2f((acc[q] - lse) * LOG2E + PSH);
    }
    __syncthreads();
    float* orow = lplT + (size_t)b * 64 * T + (size_t)lane * T + t0;
    #pragma unroll
    for (int i = 0; i < 4; ++i) {
        float4 v = make_float4(Pt2[lane][4*i], Pt2[lane][4*i+1],
                               Pt2[lane][4*i+2], Pt2[lane][4*i+3]);
        *(float4*)(orow + 4 * i) = v;
    }
    if (lane < 4) {
        float4 v = make_float4(Pb[4*lane], Pb[4*lane+1], Pb[4*lane+2], Pb[4*lane+3]);
        *(float4*)(lpb + b * T + t0 + 4 * lane) = v;
    }
}

// ---------------- K3: CTC forward, LINEAR domain, one wave per batch ---------
// lplT[b][l][t]: lane l streams its own row with float4 loads, depth-2
// register pipeline (cur/mid/far). 15-step scalar prologue aligns groups.
__global__ __launch_bounds__(64) void k_ctc(const float* __restrict__ lpb,
        const float* __restrict__ lplT, const int* __restrict__ ys,
        const int* __restrict__ hlens, const int* __restrict__ yslens,
        float* __restrict__ ll) {
    int b = blockIdx.x, l = threadIdx.x;
    int lab = ys[b * L + l];
    int labm1 = __shfl_up(lab, 1);
    bool skipB = (l >= 1) && (lab != 0) && (lab != labm1);
    int hlen = hlens[b];
    int s2 = 2 * yslens[b];
    const float* __restrict__ lpbb = lpb + b * T;
    const float* __restrict__ lpt  = lplT + (size_t)b * 64 * T + (size_t)l * T;

    __shared__ float Lb[T];
    #pragma unroll
    for (int i = 0; i < 4; ++i)
        *(float4*)&Lb[i * 256 + 4 * l] = *(const float4*)(lpbb + i * 256 + 4 * l);
    __syncthreads();

    float aA = (l == 0) ? Lb[0]   : 0.f;   // alpha0[0]
    float aB = (l == 0) ? lpt[0]  : 0.f;   // alpha0[1] (lane0's label row)
    float aE = 0.f;                        // alpha0[128] (lane 63)
    int Esum = 0;

    // issue all pipeline loads first
    float pro[15];
    #pragma unroll
    for (int u = 0; u < 15; ++u) pro[u] = lpt[1 + u];
    float4 cur[4], mid[4], far[4];
    #pragma unroll
    for (int i = 0; i < 4; ++i) cur[i] = *(const float4*)(lpt + 16 + 4 * i);
    #pragma unroll
    for (int i = 0; i < 4; ++i) mid[i] = *(const float4*)(lpt + 32 + 4 * i);

    // prologue t = 1..15
    #pragma unroll
    for (int u = 0; u < 15; ++u) {
        int t = 1 + u;
        ctc_step(aA, aB, aE, Lb[t], pro[u], skipB, t < hlen);
        if (u == 7) renorm(aA, aB, aE, Esum);
    }
    renorm(aA, aB, aE, Esum);

    // groups g=1..63: t0 = 16g, full 16 steps each (t = 16..1023)
    for (int g = 1; g < 64; ++g) {
        int t0 = 16 * g;
        if (g < 62) {
            const float* src = lpt + t0 + 32;   // group g+2
            #pragma unroll
            for (int i = 0; i < 4; ++i) far[i] = *(const float4*)(src + 4 * i);
        }
        float p[16];
        #pragma unroll
        for (int i = 0; i < 4; ++i) {
            p[4*i+0] = cur[i].x; p[4*i+1] = cur[i].y;
            p[4*i+2] = cur[i].z; p[4*i+3] = cur[i].w;
        }
        #pragma unroll
        for (int u = 0; u < 16; ++u) {
            int t = t0 + u;
            ctc_step(aA, aB, aE, Lb[t], p[u], skipB, t < hlen);
            if ((u & 7) == 7) renorm(aA, aB, aE, Esum);
        }
        #pragma unroll
        for (int i = 0; i < 4; ++i) { cur[i] = mid[i]; mid[i] = far[i]; }
    }

    int s1 = s2 - 1;
    float v1 = __shfl(aB, s1 >> 1);
    float v2 = (s2 >= 2 * L) ? __shfl(aE, 63) : __shfl(aA, s2 >> 1);
    if (l == 0)
        ll[b] = LN2 * (__log2f(v1 + v2) + (float)Esum - PSH * (float)hlen);
}

// ---------------- K4: final reduction --------------------------------------
__global__ void k_final(const float* __restrict__ ll, float* __restrict__ out) {
    if (threadIdx.x == 0 && blockIdx.x == 0) {
        float s = 0.f;
        for (int i = 0; i < B; ++i) s += ll[i];
        out[0] = -s / (float)B;
    }
}

extern "C" void kernel_launch(void* const* d_in, const int* in_sizes, int n_in,
                              void* d_out, int out_size, void* d_ws, size_t ws_size,
                              hipStream_t stream) {
    const float* hs    = (const float*)d_in[0];
    const float* W     = (const float*)d_in[1];
    const float* bias  = (const float*)d_in[2];
    const int*  hlens  = (const int*)d_in[3];
    const int*  ys     = (const int*)d_in[4];
    const int*  yslens = (const int*)d_in[5];

    char* ws = (char*)d_ws;
    unsigned* foMask = (unsigned*)(ws);            // 256 B
    float* biasG = (float*)(ws + 256);             // -> 4608
    float* Wgt   = (float*)(ws + 4608);            // -> 2232832
    float* lpb   = (float*)(ws + 2232832);         // -> 2298368
    float* lplT  = (float*)(ws + 2298368);         // [b][l][t] -> 6492672
    float* ll    = (float*)(ws + 6492672);         // 64

    hipLaunchKernelGGL(k_gather, dim3(B, 8), dim3(256), 0, stream,
                       W, bias, ys, Wgt, biasG, foMask);
    hipLaunchKernelGGL(k_scores, dim3(T / 16, B), dim3(64), 0, stream,
                       hs, Wgt, biasG, foMask, lpb, lplT);
    hipLaunchKernelGGL(k_ctc, dim3(B), dim3(64), 0, stream,
                       lpb, lplT, ys, hlens, yslens, ll);
    hipLaunchKernelGGL(k_final, dim3(1), dim3(64), 0, stream, ll, (float*)d_out);
}

// Round 9
// 125.181 us; speedup vs baseline: 7.3153x; 1.0608x over previous
//
#include <hip/hip_runtime.h>
#include <hip/hip_bf16.h>
#include <cstdint>

#define NEGV -1e30f

constexpr int B = 16, T = 1024, D = 512, V = 5000, L = 64;
constexpr int NJ = 66;   // col 0 (blank), col 1, 64 label columns
constexpr int NJP = 68;  // padded stride
#define LOG2E 1.4426950408889634f
#define LN2   0.6931471805599453f
#define PSH   6.0f   // probs pre-scaled by 2^6

template <int CTRL>
__device__ __forceinline__ float dppf(float x) {
    return __int_as_float(__builtin_amdgcn_update_dpp(
        __float_as_int(x), __float_as_int(x), CTRL, 0xf, 0xf, false));
}
__device__ __forceinline__ float shup1(float x, float fill) {
    int r = __builtin_amdgcn_update_dpp(__float_as_int(fill), __float_as_int(x),
                                        0x138 /*wave_shr:1*/, 0xf, 0xf, false);
    return __int_as_float(r);
}
__device__ __forceinline__ float wmax64(float x) {
    x = fmaxf(x, dppf<0x111>(x));
    x = fmaxf(x, dppf<0x112>(x));
    x = fmaxf(x, dppf<0x114>(x));
    x = fmaxf(x, dppf<0x118>(x));
    x = fmaxf(x, dppf<0x142>(x));
    x = fmaxf(x, dppf<0x143>(x));
    return __int_as_float(__builtin_amdgcn_readlane(__float_as_int(x), 63));
}
__device__ __forceinline__ void ctc_step(float& aA, float& aB, float& aE,
        float p_b, float p_l, float skm, bool upd) {
    float pA = shup1(aA, 0.f);
    float pB = shup1(aB, 0.f);
    float nA = (aA + pB) * p_b;
    float nB = (aB + fmaf(pA, skm, aA)) * p_l;
    float nE = (aE + aB) * p_b;
    if (upd) { aA = nA; aB = nB; aE = nE; }
}
__device__ __forceinline__ void renorm(float& aA, float& aB, float& aE, int& Esum) {
    float m = wmax64(fmaxf(fmaxf(aA, aB), aE));
    int e = ((__float_as_int(m) >> 23) & 255) - 127;
    float sc = __int_as_float((127 - e) << 23);   // exact 2^-e
    aA *= sc; aB *= sc; aE *= sc; Esum += e;
}

// ---------------- K1: gather W columns, bias, first-occurrence mask ----------
__global__ __launch_bounds__(256) void k_gather(const float* __restrict__ W,
        const float* __restrict__ bias, const int* __restrict__ ys,
        float* __restrict__ Wgt, float* __restrict__ biasG,
        unsigned* __restrict__ foMask) {
    int b = blockIdx.x, c = blockIdx.y, tid = threadIdx.x;
    __shared__ int cls[NJP];
    __shared__ unsigned mw[3];
    if (tid < NJP) cls[tid] = (tid < 2) ? tid : (tid < NJ ? ys[b * L + tid - 2] : 0);
    if (tid < 3) mw[tid] = 0u;
    __syncthreads();
    if (c == 0) {
        if (tid < NJ) {
            bool first = true;
            for (int k = 0; k < tid; ++k) if (cls[k] == cls[tid]) { first = false; break; }
            if (first) atomicOr(&mw[tid >> 5], 1u << (tid & 31));
        }
        __syncthreads();
        if (tid < 3) foMask[b * 4 + tid] = mw[tid];
        if (tid == 3) foMask[b * 4 + 3] = 0u;
        if (tid < NJP) biasG[b * NJP + tid] = (tid < NJ) ? bias[cls[tid]] : 0.f;
    }
    for (int i = tid; i < 64 * NJP; i += 256) {
        int d = c * 64 + i / NJP;
        int j = i - (i / NJP) * NJP;
        float v = (j < NJ) ? W[(size_t)d * V + cls[j]] : 0.f;
        Wgt[((size_t)b * D + d) * NJP + j] = v;
    }
}

// ---------------- K2: fused masked GEMM + deduped LSE -> scaled linear probs -
// grid (T/16, B), block 64 (1 wave). Lane (rq=lane&3, cg4=lane>>2) owns a
// 4-row x 4-col sub-tile (+1 E-col): per k only 36B/lane LDS (b128 A + b128 W
// + b32 E) instead of 68B broadcast-heavy reads. Row-LSE: stride-4 butterfly.
__global__ __launch_bounds__(64) void k_scores(const float* __restrict__ hs,
        const float* __restrict__ Wgt, const float* __restrict__ biasG,
        const unsigned* __restrict__ foMask,
        float* __restrict__ lpb, float* __restrict__ lplT) {
    int b = blockIdx.y, t0 = blockIdx.x * 16;
    int lane = threadIdx.x;
    int rq = lane & 3, cg4 = lane >> 2;
    __shared__ float Ast[64][20];   // [k][row], stride 20 -> 16B-aligned quads
    __shared__ float Ws[64][72];    // [k][col]

    const float* __restrict__ bg = biasG + b * NJP;
    float acc[4][4], accE[4];
    {
        float b0 = bg[4 * cg4 + 0], b1 = bg[4 * cg4 + 1];
        float b2 = bg[4 * cg4 + 2], b3 = bg[4 * cg4 + 3];
        float bE = bg[64 + (cg4 & 3)];
        #pragma unroll
        for (int i = 0; i < 4; ++i) {
            acc[i][0] = b0; acc[i][1] = b1; acc[i][2] = b2; acc[i][3] = b3;
            accE[i] = bE;
        }
    }

    const float* __restrict__ hsb = hs + ((size_t)(b * T + t0)) * D;
    const float* __restrict__ wgb = Wgt + (size_t)b * D * NJP;

    int srow = lane & 15, kb = (lane >> 4) * 16;
    for (int kk = 0; kk < D; kk += 64) {
        float4 a4[4];
        const float* src = hsb + (size_t)srow * D + kk + kb;
        #pragma unroll
        for (int q = 0; q < 4; ++q) a4[q] = *(const float4*)(src + q * 4);
        float4 w4[17];
        const float* wsrc = wgb + (size_t)(kk + lane) * NJP;
        #pragma unroll
        for (int q = 0; q < 17; ++q) w4[q] = *(const float4*)(wsrc + q * 4);
        __syncthreads();
        #pragma unroll
        for (int q = 0; q < 4; ++q) {
            Ast[kb + 4 * q + 0][srow] = a4[q].x;
            Ast[kb + 4 * q + 1][srow] = a4[q].y;
            Ast[kb + 4 * q + 2][srow] = a4[q].z;
            Ast[kb + 4 * q + 3][srow] = a4[q].w;
        }
        #pragma unroll
        for (int q = 0; q < 17; ++q) *(float4*)&Ws[lane][4 * q] = w4[q];
        __syncthreads();
        #pragma unroll 4
        for (int k = 0; k < 64; ++k) {
            float4 av = *(const float4*)&Ast[k][4 * rq];
            float4 wv = *(const float4*)&Ws[k][4 * cg4];
            float  ev = Ws[k][64 + (cg4 & 3)];
            float a_[4] = {av.x, av.y, av.z, av.w};
            #pragma unroll
            for (int i = 0; i < 4; ++i) {
                acc[i][0] = fmaf(a_[i], wv.x, acc[i][0]);
                acc[i][1] = fmaf(a_[i], wv.y, acc[i][1]);
                acc[i][2] = fmaf(a_[i], wv.z, acc[i][2]);
                acc[i][3] = fmaf(a_[i], wv.w, acc[i][3]);
                accE[i]   = fmaf(a_[i], ev,   accE[i]);
            }
        }
    }

    // per-row (t) deduped LSE over 16 lanes sharing rq (stride-4 butterfly)
    unsigned m0 = foMask[b * 4 + 0], m1 = foMask[b * 4 + 1], m2 = foMask[b * 4 + 2];
    unsigned mwrd = (cg4 < 8) ? m0 : m1;
    unsigned mq0 = (mwrd >> ((4 * cg4 + 0) & 31)) & 1u;
    unsigned mq1 = (mwrd >> ((4 * cg4 + 1) & 31)) & 1u;
    unsigned mq2 = (mwrd >> ((4 * cg4 + 2) & 31)) & 1u;
    unsigned mq3 = (mwrd >> ((4 * cg4 + 3) & 31)) & 1u;
    unsigned mE  = (cg4 < 4) ? ((m2 >> cg4) & 1u) : 0u;
    float lse[4];
    #pragma unroll
    for (int i = 0; i < 4; ++i) {
        float m_ = NEGV;
        if (mq0) m_ = fmaxf(m_, acc[i][0]);
        if (mq1) m_ = fmaxf(m_, acc[i][1]);
        if (mq2) m_ = fmaxf(m_, acc[i][2]);
        if (mq3) m_ = fmaxf(m_, acc[i][3]);
        if (mE)  m_ = fmaxf(m_, accE[i]);
        m_ = fmaxf(m_, __shfl_xor(m_, 4));
        m_ = fmaxf(m_, __shfl_xor(m_, 8));
        m_ = fmaxf(m_, __shfl_xor(m_, 16));
        m_ = fmaxf(m_, __shfl_xor(m_, 32));
        float s_ = 0.f;
        if (mq0) s_ += __expf(acc[i][0] - m_);
        if (mq1) s_ += __expf(acc[i][1] - m_);
        if (mq2) s_ += __expf(acc[i][2] - m_);
        if (mq3) s_ += __expf(acc[i][3] - m_);
        if (mE)  s_ += __expf(accE[i] - m_);
        s_ += __shfl_xor(s_, 4);
        s_ += __shfl_xor(s_, 8);
        s_ += __shfl_xor(s_, 16);
        s_ += __shfl_xor(s_, 32);
        lse[i] = m_ + __logf(s_);
    }

    // epilogue: p = exp2(lp2+6) -> LDS transpose [label][t] -> float4 stores
    float (*Pt2)[20] = (float(*)[20])&Ws[0][0];   // 64 x 20 (16B-aligned rows)
    float* Pb = &Ast[0][0];                        // 16 blanks
    __syncthreads();
    #pragma unroll
    for (int i = 0; i < 4; ++i) {
        int t = 4 * rq + i;
        #pragma unroll
        for (int q = 0; q < 4; ++q) {
            int c = 4 * cg4 + q;
            float pr = exp2f((acc[i][q] - lse[i]) * LOG2E + PSH);
            if (c == 0) Pb[t] = pr;
            else if (c >= 2) Pt2[c - 2][t] = pr;
        }
        if (cg4 < 2) Pt2[62 + cg4][t] = exp2f((accE[i] - lse[i]) * LOG2E + PSH);
    }
    __syncthreads();
    float* orow = lplT + (size_t)b * 64 * T + (size_t)lane * T + t0;
    #pragma unroll
    for (int i = 0; i < 4; ++i)
        *(float4*)(orow + 4 * i) = *(const float4*)&Pt2[lane][4 * i];
    if (lane < 4) {
        float4 v = make_float4(Pb[4*lane], Pb[4*lane+1], Pb[4*lane+2], Pb[4*lane+3]);
        *(float4*)(lpb + b * T + t0 + 4 * lane) = v;
    }
}

// ---------------- K3: CTC forward, LINEAR domain, one wave per batch ---------
__global__ __launch_bounds__(64) void k_ctc(const float* __restrict__ lpb,
        const float* __restrict__ lplT, const int* __restrict__ ys,
        const int* __restrict__ hlens, const int* __restrict__ yslens,
        float* __restrict__ ll) {
    int b = blockIdx.x, l = threadIdx.x;
    int lab = ys[b * L + l];
    int labm1 = __shfl_up(lab, 1);
    float skm = ((l >= 1) && (lab != 0) && (lab != labm1)) ? 1.0f : 0.0f;
    int hlen = hlens[b];
    int s2 = 2 * yslens[b];
    const float* __restrict__ lpbb = lpb + b * T;
    const float* __restrict__ lpt  = lplT + (size_t)b * 64 * T + (size_t)l * T;

    __shared__ float Lb[T];
    #pragma unroll
    for (int i = 0; i < 4; ++i)
        *(float4*)&Lb[i * 256 + 4 * l] = *(const float4*)(lpbb + i * 256 + 4 * l);
    __syncthreads();

    float aA = (l == 0) ? Lb[0]   : 0.f;
    float aB = (l == 0) ? lpt[0]  : 0.f;
    float aE = 0.f;
    int Esum = 0;

    float pro[15];
    #pragma unroll
    for (int u = 0; u < 15; ++u) pro[u] = lpt[1 + u];
    float4 cur[4], mid[4], far[4];
    #pragma unroll
    for (int i = 0; i < 4; ++i) cur[i] = *(const float4*)(lpt + 16 + 4 * i);
    #pragma unroll
    for (int i = 0; i < 4; ++i) mid[i] = *(const float4*)(lpt + 32 + 4 * i);

    #pragma unroll
    for (int u = 0; u < 15; ++u) {
        int t = 1 + u;
        ctc_step(aA, aB, aE, Lb[t], pro[u], skm, t < hlen);
    }
    renorm(aA, aB, aE, Esum);

    for (int g = 1; g < 64; ++g) {
        int t0 = 16 * g;
        if (g < 62) {
            const float* src = lpt + t0 + 32;
            #pragma unroll
            for (int i = 0; i < 4; ++i) far[i] = *(const float4*)(src + 4 * i);
        }
        float p[16];
        #pragma unroll
        for (int i = 0; i < 4; ++i) {
            p[4*i+0] = cur[i].x; p[4*i+1] = cur[i].y;
            p[4*i+2] = cur[i].z; p[4*i+3] = cur[i].w;
        }
        #pragma unroll
        for (int u = 0; u < 16; ++u) {
            int t = t0 + u;
            ctc_step(aA, aB, aE, Lb[t], p[u], skm, t < hlen);
        }
        renorm(aA, aB, aE, Esum);   // every 16 steps (2^122 worst-case < inf)
        #pragma unroll
        for (int i = 0; i < 4; ++i) { cur[i] = mid[i]; mid[i] = far[i]; }
    }

    int s1 = s2 - 1;
    float v1 = __shfl(aB, s1 >> 1);
    float v2 = (s2 >= 2 * L) ? __shfl(aE, 63) : __shfl(aA, s2 >> 1);
    if (l == 0)
        ll[b] = LN2 * (__log2f(v1 + v2) + (float)Esum - PSH * (float)hlen);
}

// ---------------- K4: final reduction --------------------------------------
__global__ void k_final(const float* __restrict__ ll, float* __restrict__ out) {
    if (threadIdx.x == 0 && blockIdx.x == 0) {
        float s = 0.f;
        for (int i = 0; i < B; ++i) s += ll[i];
        out[0] = -s / (float)B;
    }
}

extern "C" void kernel_launch(void* const* d_in, const int* in_sizes, int n_in,
                              void* d_out, int out_size, void* d_ws, size_t ws_size,
                              hipStream_t stream) {
    const float* hs    = (const float*)d_in[0];
    const float* W     = (const float*)d_in[1];
    const float* bias  = (const float*)d_in[2];
    const int*  hlens  = (const int*)d_in[3];
    const int*  ys     = (const int*)d_in[4];
    const int*  yslens = (const int*)d_in[5];

    char* ws = (char*)d_ws;
    unsigned* foMask = (unsigned*)(ws);            // 256 B
    float* biasG = (float*)(ws + 256);             // -> 4608
    float* Wgt   = (float*)(ws + 4608);            // -> 2232832
    float* lpb   = (float*)(ws + 2232832);         // -> 2298368
    float* lplT  = (float*)(ws + 2298368);         // [b][l][t] -> 6492672
    float* ll    = (float*)(ws + 6492672);         // 64

    hipLaunchKernelGGL(k_gather, dim3(B, 8), dim3(256), 0, stream,
                       W, bias, ys, Wgt, biasG, foMask);
    hipLaunchKernelGGL(k_scores, dim3(T / 16, B), dim3(64), 0, stream,
                       hs, Wgt, biasG, foMask, lpb, lplT);
    hipLaunchKernelGGL(k_ctc, dim3(B), dim3(64), 0, stream,
                       lpb, lplT, ys, hlens, yslens, ll);
    hipLaunchKernelGGL(k_final, dim3(1), dim3(64), 0, stream, ll, (float*)d_out);
}

// Round 10
// 71.563 us; speedup vs baseline: 12.7962x; 1.7492x over previous
//
#include <hip/hip_runtime.h>
#include <hip/hip_bf16.h>
#include <cstdint>

#define NEGV -1e30f

constexpr int B = 16, T = 1024, D = 512, V = 5000, L = 64;
constexpr int NJ = 66;    // col 0 blank, col 1 class-1, cols 2..65 = labels
constexpr int NJP = 80;   // padded col count (5 MFMA n-tiles of 16)
#define LOG2E 1.4426950408889634f
#define LN2   0.6931471805599453f
#define PSH   6.0f   // probs pre-scaled by 2^6

typedef __attribute__((ext_vector_type(8))) short bf16x8;
typedef __attribute__((ext_vector_type(4))) int   i32x4;
typedef __attribute__((ext_vector_type(4))) float f32x4;

template <int CTRL>
__device__ __forceinline__ float dppf(float x) {
    return __int_as_float(__builtin_amdgcn_update_dpp(
        __float_as_int(x), __float_as_int(x), CTRL, 0xf, 0xf, false));
}
__device__ __forceinline__ float shup1(float x, float fill) {
    int r = __builtin_amdgcn_update_dpp(__float_as_int(fill), __float_as_int(x),
                                        0x138 /*wave_shr:1*/, 0xf, 0xf, false);
    return __int_as_float(r);
}
__device__ __forceinline__ float wmax64(float x) {
    x = fmaxf(x, dppf<0x111>(x));
    x = fmaxf(x, dppf<0x112>(x));
    x = fmaxf(x, dppf<0x114>(x));
    x = fmaxf(x, dppf<0x118>(x));
    x = fmaxf(x, dppf<0x142>(x));
    x = fmaxf(x, dppf<0x143>(x));
    return __int_as_float(__builtin_amdgcn_readlane(__float_as_int(x), 63));
}
// guarded step (prologue/tail)
__device__ __forceinline__ void ctc_step_g(float& aA, float& aB, float& aE,
        float p_b, float p_l, float skm, bool upd) {
    float pA = shup1(aA, 0.f);
    float pB = shup1(aB, 0.f);
    float nA = (aA + pB) * p_b;
    float nB = (aB + fmaf(pA, skm, aA)) * p_l;
    float nE = (aE + aB) * p_b;
    if (upd) { aA = nA; aB = nB; aE = nE; }
}
// unguarded step (full groups): chain = dpp + fma/add + mul
__device__ __forceinline__ void ctc_step_u(float& aA, float& aB, float& aE,
        float p_b, float p_l, float skm) {
    float pA = shup1(aA, 0.f);
    float pB = shup1(aB, 0.f);
    float nA = (aA + pB) * p_b;
    float nB = (aB + fmaf(pA, skm, aA)) * p_l;
    float nE = (aE + aB) * p_b;
    aA = nA; aB = nB; aE = nE;
}
__device__ __forceinline__ void renorm(float& aA, float& aB, float& aE, int& Esum) {
    float m = wmax64(fmaxf(fmaxf(aA, aB), aE));
    int e = ((__float_as_int(m) >> 23) & 255) - 127;
    float sc = __int_as_float((127 - e) << 23);   // exact 2^-e
    aA *= sc; aB *= sc; aE *= sc; Esum += e;
}
__device__ __forceinline__ int pk2(float lo, float hi) {   // 2xf32 -> 2xbf16 (trunc)
    return (int)((__float_as_uint(hi) & 0xFFFF0000u) | (__float_as_uint(lo) >> 16));
}

// ---------------- K1: gather W cols -> bf16 WgtT[b][80][512], bias, mask -----
// grid (B, 8): block (b,c) handles k-range [64c, 64c+64). 256 thr = 64 k x 4 j.
__global__ __launch_bounds__(256) void k_gather(const float* __restrict__ W,
        const float* __restrict__ bias, const int* __restrict__ ys,
        short* __restrict__ WgtT, float* __restrict__ biasG,
        unsigned* __restrict__ foMask) {
    int b = blockIdx.x, c = blockIdx.y, tid = threadIdx.x;
    __shared__ int cls[NJP];
    __shared__ unsigned mw[3];
    if (tid < NJP) cls[tid] = (tid < 2) ? tid : (tid < NJ ? ys[b * L + tid - 2] : 0);
    if (tid < 3) mw[tid] = 0u;
    __syncthreads();
    if (c == 0) {
        if (tid < NJ) {
            bool first = true;
            for (int k = 0; k < tid; ++k) if (cls[k] == cls[tid]) { first = false; break; }
            if (first) atomicOr(&mw[tid >> 5], 1u << (tid & 31));
        }
        __syncthreads();
        if (tid < 3) foMask[b * 4 + tid] = mw[tid];
        if (tid == 3) foMask[b * 4 + 3] = 0u;
        if (tid < NJP) biasG[b * NJP + tid] = (tid < NJ) ? bias[cls[tid]] : 0.f;
    }
    int kt = tid & 63, jg = tid >> 6;
    for (int j = jg; j < NJP; j += 4) {
        int d = c * 64 + kt;
        float v = (j < NJ) ? W[(size_t)d * V + cls[j]] : 0.f;
        WgtT[((size_t)b * NJP + j) * D + d] = (short)(__float_as_uint(v) >> 16);
    }
}

// ---------------- K2: MFMA masked GEMM + deduped LSE -> scaled linear probs --
// grid (T/16, B), block 64 (1 wave). 16 t-rows x 80 cols via 5x
// mfma_f32_16x16x32_bf16 per K=32 step. A from hs (f32->bf16 inline), B from
// WgtT bf16 -- both 16B-contiguous per-lane global loads; no LDS in K-loop.
__global__ __launch_bounds__(64) void k_scores(const float* __restrict__ hs,
        const short* __restrict__ WgtT, const float* __restrict__ biasG,
        const unsigned* __restrict__ foMask,
        float* __restrict__ lpb, float* __restrict__ lplT) {
    int b = blockIdx.y, t0 = blockIdx.x * 16;
    int lane = threadIdx.x, cl = lane & 15, kg = lane >> 4;

    f32x4 acc[5];
    const float* __restrict__ bg = biasG + b * NJP;
    #pragma unroll
    for (int nt = 0; nt < 5; ++nt) {
        float bv = bg[nt * 16 + cl];
        acc[nt] = (f32x4){bv, bv, bv, bv};
    }

    const float* __restrict__ arow = hs + ((size_t)(b * T) + t0 + cl) * D + kg * 8;
    const short* __restrict__ brow = WgtT + ((size_t)b * NJP + cl) * D + kg * 8;

    #pragma unroll 4
    for (int ks = 0; ks < 16; ++ks) {
        int k0 = ks * 32;
        float4 a0 = *(const float4*)(arow + k0);
        float4 a1 = *(const float4*)(arow + k0 + 4);
        i32x4 ap = { pk2(a0.x, a0.y), pk2(a0.z, a0.w),
                     pk2(a1.x, a1.y), pk2(a1.z, a1.w) };
        bf16x8 af = __builtin_bit_cast(bf16x8, ap);
        #pragma unroll
        for (int nt = 0; nt < 5; ++nt) {
            bf16x8 bf = *(const bf16x8*)(brow + (size_t)nt * 16 * D + k0);
            acc[nt] = __builtin_amdgcn_mfma_f32_16x16x32_bf16(af, bf, acc[nt], 0, 0, 0);
        }
    }

    // C/D: col = nt*16 + cl, row(t_local) = kg*4 + r   [HW-verified layout]
    unsigned m0 = foMask[b * 4 + 0], m1 = foMask[b * 4 + 1], m2 = foMask[b * 4 + 2];
    bool on[5];
    on[0] = (m0 >> cl) & 1;        on[1] = (m0 >> (16 + cl)) & 1;
    on[2] = (m1 >> cl) & 1;        on[3] = (m1 >> (16 + cl)) & 1;
    on[4] = (cl < 2) ? ((m2 >> cl) & 1) : false;

    float lse[4];
    #pragma unroll
    for (int r = 0; r < 4; ++r) {
        float mx = NEGV;
        #pragma unroll
        for (int nt = 0; nt < 5; ++nt) if (on[nt]) mx = fmaxf(mx, acc[nt][r]);
        mx = fmaxf(mx, __shfl_xor(mx, 1));
        mx = fmaxf(mx, __shfl_xor(mx, 2));
        mx = fmaxf(mx, __shfl_xor(mx, 4));
        mx = fmaxf(mx, __shfl_xor(mx, 8));
        float s = 0.f;
        #pragma unroll
        for (int nt = 0; nt < 5; ++nt) if (on[nt]) s += __expf(acc[nt][r] - mx);
        s += __shfl_xor(s, 1);
        s += __shfl_xor(s, 2);
        s += __shfl_xor(s, 4);
        s += __shfl_xor(s, 8);
        lse[r] = mx + __logf(s);
    }

    // epilogue: p = exp2(lp2+6) -> LDS transpose [label][t] -> float4 stores
    __shared__ float Pt2[64][20];   // label x t_local (rows 80B, 16B-aligned)
    __shared__ float Pb[16];
    #pragma unroll
    for (int nt = 0; nt < 5; ++nt) {
        int col = nt * 16 + cl;
        #pragma unroll
        for (int r = 0; r < 4; ++r) {
            int t = kg * 4 + r;
            float pv = exp2f((acc[nt][r] - lse[r]) * LOG2E + PSH);
            if (col == 0) Pb[t] = pv;
            else if (col >= 2 && col < NJ) Pt2[col - 2][t] = pv;
        }
    }
    __syncthreads();
    float* __restrict__ orow = lplT + (size_t)b * 64 * T + (size_t)lane * T + t0;
    #pragma unroll
    for (int i = 0; i < 4; ++i)
        *(float4*)(orow + 4 * i) = *(const float4*)&Pt2[lane][4 * i];
    if (lane < 4) {
        float4 v = make_float4(Pb[4*lane], Pb[4*lane+1], Pb[4*lane+2], Pb[4*lane+3]);
        *(float4*)(lpb + b * T + t0 + 4 * lane) = v;
    }
}

// ---------------- K3: CTC forward, LINEAR domain, one wave per batch ---------
__global__ __launch_bounds__(64) void k_ctc(const float* __restrict__ lpb,
        const float* __restrict__ lplT, const int* __restrict__ ys,
        const int* __restrict__ hlens, const int* __restrict__ yslens,
        float* __restrict__ ll) {
    int b = blockIdx.x, l = threadIdx.x;
    int lab = ys[b * L + l];
    int labm1 = __shfl_up(lab, 1);
    float skm = ((l >= 1) && (lab != 0) && (lab != labm1)) ? 1.0f : 0.0f;
    int hlen = hlens[b];
    int s2 = 2 * yslens[b];
    const float* __restrict__ lpbb = lpb + b * T;
    const float* __restrict__ lpt  = lplT + (size_t)b * 64 * T + (size_t)l * T;

    __shared__ float Lb[T];
    #pragma unroll
    for (int i = 0; i < 4; ++i)
        *(float4*)&Lb[i * 256 + 4 * l] = *(const float4*)(lpbb + i * 256 + 4 * l);
    __syncthreads();

    float aA = (l == 0) ? Lb[0]   : 0.f;
    float aB = (l == 0) ? lpt[0]  : 0.f;
    float aE = 0.f;
    int Esum = 0;

    float pro[15];
    #pragma unroll
    for (int u = 0; u < 15; ++u) pro[u] = lpt[1 + u];
    float4 cur[4], mid[4], far[4];
    #pragma unroll
    for (int i = 0; i < 4; ++i) cur[i] = *(const float4*)(lpt + 16 + 4 * i);
    #pragma unroll
    for (int i = 0; i < 4; ++i) mid[i] = *(const float4*)(lpt + 32 + 4 * i);

    #pragma unroll
    for (int u = 0; u < 15; ++u) {
        int t = 1 + u;
        ctc_step_g(aA, aB, aE, Lb[t], pro[u], skm, t < hlen);
    }
    renorm(aA, aB, aE, Esum);

    for (int g = 1; g < 64; ++g) {
        int t0 = 16 * g;
        if (g < 62) {
            const float* src = lpt + t0 + 32;
            #pragma unroll
            for (int i = 0; i < 4; ++i) far[i] = *(const float4*)(src + 4 * i);
        }
        float p[16];
        #pragma unroll
        for (int i = 0; i < 4; ++i) {
            p[4*i+0] = cur[i].x; p[4*i+1] = cur[i].y;
            p[4*i+2] = cur[i].z; p[4*i+3] = cur[i].w;
        }
        if (t0 + 16 <= hlen) {          // full group: no per-step guard
            #pragma unroll
            for (int u = 0; u < 16; ++u)
                ctc_step_u(aA, aB, aE, Lb[t0 + u], p[u], skm);
        } else {                        // tail/past-end: guarded (no-ops past hlen)
            #pragma unroll
            for (int u = 0; u < 16; ++u) {
                int t = t0 + u;
                ctc_step_g(aA, aB, aE, Lb[t], p[u], skm, t < hlen);
            }
        }
        renorm(aA, aB, aE, Esum);   // every 16 steps (2^122 worst-case < inf)
        #pragma unroll
        for (int i = 0; i < 4; ++i) { cur[i] = mid[i]; mid[i] = far[i]; }
    }

    int s1 = s2 - 1;
    float v1 = __shfl(aB, s1 >> 1);
    float v2 = (s2 >= 2 * L) ? __shfl(aE, 63) : __shfl(aA, s2 >> 1);
    if (l == 0)
        ll[b] = LN2 * (__log2f(v1 + v2) + (float)Esum - PSH * (float)hlen);
}

// ---------------- K4: final reduction --------------------------------------
__global__ void k_final(const float* __restrict__ ll, float* __restrict__ out) {
    if (threadIdx.x == 0 && blockIdx.x == 0) {
        float s = 0.f;
        for (int i = 0; i < B; ++i) s += ll[i];
        out[0] = -s / (float)B;
    }
}

extern "C" void kernel_launch(void* const* d_in, const int* in_sizes, int n_in,
                              void* d_out, int out_size, void* d_ws, size_t ws_size,
                              hipStream_t stream) {
    const float* hs    = (const float*)d_in[0];
    const float* W     = (const float*)d_in[1];
    const float* bias  = (const float*)d_in[2];
    const int*  hlens  = (const int*)d_in[3];
    const int*  ys     = (const int*)d_in[4];
    const int*  yslens = (const int*)d_in[5];

    char* ws = (char*)d_ws;
    unsigned* foMask = (unsigned*)(ws);            // 256 B
    float* biasG = (float*)(ws + 256);             // 16*80*4   -> 5376
    short* WgtT  = (short*)(ws + 5376);            // 16*80*512*2 -> 1316096
    float* lpb   = (float*)(ws + 1316096);         // 64 KB     -> 1381632
    float* lplT  = (float*)(ws + 1381632);         // [b][l][t] -> 5575936
    float* ll    = (float*)(ws + 5575936);         // 64

    hipLaunchKernelGGL(k_gather, dim3(B, 8), dim3(256), 0, stream,
                       W, bias, ys, WgtT, biasG, foMask);
    hipLaunchKernelGGL(k_scores, dim3(T / 16, B), dim3(64), 0, stream,
                       hs, WgtT, biasG, foMask, lpb, lplT);
    hipLaunchKernelGGL(k_ctc, dim3(B), dim3(64), 0, stream,
                       lpb, lplT, ys, hlens, yslens, ll);
    hipLaunchKernelGGL(k_final, dim3(1), dim3(64), 0, stream, ll, (float*)d_out);
}